// Round 7
// baseline (708.622 us; speedup 1.0000x reference)
//
#include <hip/hip_runtime.h>

#define BN_EPS 1e-5f

typedef _Float16 f16;
typedef _Float16 f16x8 __attribute__((ext_vector_type(8)));
typedef _Float16 f16x4 __attribute__((ext_vector_type(4)));
typedef float f32x4 __attribute__((ext_vector_type(4)));

// ================= x -> f16 convert =================
__global__ __launch_bounds__(256) void conv_kernel(const float4* __restrict__ in,
        f16x4* __restrict__ out, int n4) {
    int i = blockIdx.x * 256 + threadIdx.x;
    if (i < n4) {
        float4 v = in[i];
        f16x4 o;
        o.x = (f16)v.x; o.y = (f16)v.y; o.z = (f16)v.z; o.w = (f16)v.w;
        out[i] = o;
    }
}

// ================= CSR build (8-way privatized histogram) =================
// rank[e] = local rank within copy c (c = blockIdx.x & 7)
__global__ __launch_bounds__(256) void hist_kernel(const int* __restrict__ dst,
        int* __restrict__ deg8, int* __restrict__ rank, int N, int E) {
    int e = blockIdx.x * 256 + threadIdx.x;
    if (e < E) rank[e] = atomicAdd(&deg8[(blockIdx.x & 7) * N + dst[e]], 1);
}

// per-node: total deg + per-copy exclusive offsets (in place)
__global__ __launch_bounds__(256) void combine_kernel(int* __restrict__ deg8,
        int* __restrict__ deg, int N) {
    int g = blockIdx.x * 256 + threadIdx.x;
    if (g >= N) return;
    int s = 0;
#pragma unroll
    for (int c = 0; c < 8; c++) {
        int t = deg8[c * N + g];
        deg8[c * N + g] = s;
        s += t;
    }
    deg[g] = s;
}

__global__ __launch_bounds__(1024) void scan_block(const int* __restrict__ deg,
        int* __restrict__ off, int* __restrict__ bsum, int N) {
    __shared__ int sh[1024];
    int g = blockIdx.x * 1024 + threadIdx.x;
    int v = (g < N) ? deg[g] : 0;
    sh[threadIdx.x] = v;
    __syncthreads();
    for (int d = 1; d < 1024; d <<= 1) {
        int t = (threadIdx.x >= d) ? sh[threadIdx.x - d] : 0;
        __syncthreads();
        sh[threadIdx.x] += t;
        __syncthreads();
    }
    if (g < N) off[g + 1] = sh[threadIdx.x];
    if (threadIdx.x == 1023) bsum[blockIdx.x] = sh[1023];
    if (g == 0) off[0] = 0;
}

__global__ __launch_bounds__(128) void scan_bsum(int* __restrict__ bsum, int nb) {
    __shared__ int sh[128];
    int v = (threadIdx.x < nb) ? bsum[threadIdx.x] : 0;
    sh[threadIdx.x] = v;
    __syncthreads();
    for (int d = 1; d < 128; d <<= 1) {
        int t = (threadIdx.x >= d) ? sh[threadIdx.x - d] : 0;
        __syncthreads();
        sh[threadIdx.x] += t;
        __syncthreads();
    }
    if (threadIdx.x < nb) bsum[threadIdx.x] = sh[threadIdx.x] - v;  // exclusive
}

__global__ __launch_bounds__(1024) void scan_finish(int* __restrict__ off,
        const int* __restrict__ bsum, int N) {
    int g = blockIdx.x * 1024 + threadIdx.x;
    if (g < N) off[g + 1] += bsum[blockIdx.x];
}

// slot = off[dst] + copy_offset[c][dst] + local rank  (grid must match hist!)
__global__ __launch_bounds__(256) void fill_kernel(const int* __restrict__ src,
        const int* __restrict__ dst, const int* __restrict__ rank,
        const int* __restrict__ off, const int* __restrict__ deg8,
        int* __restrict__ elist, int N, int E) {
    int e = blockIdx.x * 256 + threadIdx.x;
    if (e < E) {
        int d = dst[e];
        elist[off[d] + deg8[(blockIdx.x & 7) * N + d] + rank[e]] = src[e];
    }
}

// ================= vectorized gather (f16x8 = 16B per lane) ===================
// AFFINE==false: out[i] = in[i] + sum_{s in nbrs} in[s]
// AFFINE==true : out[i] = relu( acc + cnt*v + b ),  cnt = deg+1
template<int F, bool AFFINE>
__global__ __launch_bounds__(256) void gather_v(const int* __restrict__ off,
        const int* __restrict__ elist, const f16* __restrict__ in,
        f16* __restrict__ out, const float* __restrict__ v,
        const float* __restrict__ bias, int N) {
    constexpr int TPN = F / 8;           // threads per node
    constexpr int NPB = 256 / TPN;       // nodes per block
    const int i = blockIdx.x * NPB + threadIdx.x / TPN;
    const int l = threadIdx.x & (TPN - 1);
    if (i >= N) return;
    const int j0 = l * 8;
    f16x8 s = ((const f16x8*)(in + (size_t)i * F))[l];
    float a[8];
#pragma unroll
    for (int u = 0; u < 8; u++) a[u] = (float)s[u];
    int k = off[i], e = off[i + 1];
    const float cnt = (float)(e - k + 1);
    for (; k + 4 <= e; k += 4) {
        int n0 = elist[k], n1 = elist[k + 1], n2 = elist[k + 2], n3 = elist[k + 3];
        f16x8 p0 = ((const f16x8*)(in + (size_t)n0 * F))[l];
        f16x8 p1 = ((const f16x8*)(in + (size_t)n1 * F))[l];
        f16x8 p2 = ((const f16x8*)(in + (size_t)n2 * F))[l];
        f16x8 p3 = ((const f16x8*)(in + (size_t)n3 * F))[l];
#pragma unroll
        for (int u = 0; u < 8; u++)
            a[u] += ((float)p0[u] + (float)p1[u]) + ((float)p2[u] + (float)p3[u]);
    }
    for (; k < e; k++) {
        f16x8 p = ((const f16x8*)(in + (size_t)elist[k] * F))[l];
#pragma unroll
        for (int u = 0; u < 8; u++) a[u] += (float)p[u];
    }
    if (AFFINE) {
        float4 vv0 = *(const float4*)(v + j0);
        float4 vv1 = *(const float4*)(v + j0 + 4);
        float4 bb0 = *(const float4*)(bias + j0);
        float4 bb1 = *(const float4*)(bias + j0 + 4);
        a[0] = fmaxf(fmaf(cnt, vv0.x, a[0] + bb0.x), 0.0f);
        a[1] = fmaxf(fmaf(cnt, vv0.y, a[1] + bb0.y), 0.0f);
        a[2] = fmaxf(fmaf(cnt, vv0.z, a[2] + bb0.z), 0.0f);
        a[3] = fmaxf(fmaf(cnt, vv0.w, a[3] + bb0.w), 0.0f);
        a[4] = fmaxf(fmaf(cnt, vv1.x, a[4] + bb1.x), 0.0f);
        a[5] = fmaxf(fmaf(cnt, vv1.y, a[5] + bb1.y), 0.0f);
        a[6] = fmaxf(fmaf(cnt, vv1.z, a[6] + bb1.z), 0.0f);
        a[7] = fmaxf(fmaf(cnt, vv1.w, a[7] + bb1.w), 0.0f);
    }
    f16x8 o;
#pragma unroll
    for (int u = 0; u < 8; u++) o[u] = (f16)a[u];
    ((f16x8*)(out + (size_t)i * F))[l] = o;
}

// ================= prep: v[j] = sum_k sh[k] * W[k][j] =========================
__global__ __launch_bounds__(64) void prep_kernel(const float* __restrict__ W,
        const float* __restrict__ stats, const float* __restrict__ g,
        const float* __restrict__ be, float* __restrict__ v,
        int FIN, int FOUT, float invN) {
    int j = threadIdx.x;
    if (j >= FOUT) return;
    float acc = 0.0f;
    for (int k = 0; k < FIN; k++) {
        float mu = stats[k] * invN;
        float var = fmaxf(stats[FIN + k] * invN - mu * mu, 0.0f);
        float sc = rsqrtf(var + BN_EPS) * g[k];
        float sh = be[k] - mu * sc;
        acc = fmaf(sh, W[(size_t)k * FOUT + j], acc);
    }
    v[j] = acc;
}

// ================= MFMA GEMM ==================================================
// Out = [relu]( A @ (diag(sc)? W) + (bias?) ), optional col stats of output.
// A: [N,FIN] f16, W: [FIN,FOUT] f32. One wave per 16-row stripe. N % 16 == 0.
template<int FIN, int FOUT, bool STATS, bool RELU, bool BIAS, bool BNW, typename OutT>
__global__ __launch_bounds__(256) void gemm_mfma(const f16* __restrict__ A,
        const float* __restrict__ W, const float* __restrict__ bias,
        OutT* __restrict__ Out, float* __restrict__ stats,
        const float* __restrict__ bnstats, const float* __restrict__ bng,
        float invN, int N) {
    constexpr int NS = FIN / 32;    // k-steps
    constexpr int NT = FOUT / 16;   // n-tiles
    __shared__ f16 Wl[NS * NT * 512];
    __shared__ float Bl[BIAS ? FOUT : 1];
    __shared__ float Ss[STATS ? 2 * FOUT : 1];
    __shared__ float Scs[BNW ? FIN : 1];

    if (BNW) {
        for (int k = threadIdx.x; k < FIN; k += 256) {
            float mu = bnstats[k] * invN;
            float var = fmaxf(bnstats[FIN + k] * invN - mu * mu, 0.0f);
            Scs[k] = rsqrtf(var + BN_EPS) * bng[k];
        }
        __syncthreads();
    }
    for (int i = threadIdx.x; i < FIN * FOUT; i += 256) {
        int k = i / FOUT, n = i & (FOUT - 1);
        int s = k >> 5, kk = k & 31;
        int lane = (n & 15) | ((kk >> 3) << 4);
        int j = kk & 7;
        float wv = W[i];
        if (BNW) wv *= Scs[k];
        Wl[(((s * NT) + (n >> 4)) << 9) + (lane << 3) + j] = (f16)wv;
    }
    if (BIAS && threadIdx.x < FOUT) Bl[threadIdx.x] = bias[threadIdx.x];
    if (STATS) for (int i = threadIdx.x; i < 2 * FOUT; i += 256) Ss[i] = 0.0f;
    __syncthreads();

    const int wid = threadIdx.x >> 6;
    const int lane = threadIdx.x & 63;
    const int col = lane & 15;
    const int quad = lane >> 4;

    f16x8 Bf[NS][NT];
#pragma unroll
    for (int s = 0; s < NS; s++)
#pragma unroll
        for (int t = 0; t < NT; t++)
            Bf[s][t] = *(const f16x8*)&Wl[((s * NT + t) << 9) + (lane << 3)];

    float ls[NT], ls2[NT];
#pragma unroll
    for (int t = 0; t < NT; t++) { ls[t] = 0.0f; ls2[t] = 0.0f; }

    const int S = N >> 4;
    for (int sidx = blockIdx.x * 4 + wid; sidx < S; sidx += (int)gridDim.x * 4) {
        const int m0 = sidx << 4;
        const f16* a0 = A + (size_t)(m0 + col) * FIN + (quad << 3);
        f16x8 Af[NS];
#pragma unroll
        for (int s = 0; s < NS; s++) Af[s] = *(const f16x8*)(a0 + s * 32);
        f32x4 acc[NT];
#pragma unroll
        for (int t = 0; t < NT; t++) {
            float b = BIAS ? Bl[t * 16 + col] : 0.0f;
            acc[t] = (f32x4){b, b, b, b};
        }
#pragma unroll
        for (int t = 0; t < NT; t++)
#pragma unroll
            for (int s = 0; s < NS; s++)
                acc[t] = __builtin_amdgcn_mfma_f32_16x16x32_f16(Af[s], Bf[s][t], acc[t], 0, 0, 0);
#pragma unroll
        for (int t = 0; t < NT; t++) {
            float v0 = acc[t][0], v1 = acc[t][1], v2 = acc[t][2], v3 = acc[t][3];
            if (RELU) {
                v0 = fmaxf(v0, 0.0f); v1 = fmaxf(v1, 0.0f);
                v2 = fmaxf(v2, 0.0f); v3 = fmaxf(v3, 0.0f);
            }
            if (STATS) {
                ls[t]  += (v0 + v1) + (v2 + v3);
                ls2[t] += (v0 * v0 + v1 * v1) + (v2 * v2 + v3 * v3);
            }
            OutT* o = Out + (size_t)(m0 + quad * 4) * FOUT + t * 16 + col;
            o[0]        = (OutT)v0;
            o[FOUT]     = (OutT)v1;
            o[2 * FOUT] = (OutT)v2;
            o[3 * FOUT] = (OutT)v3;
        }
    }

    if (STATS) {
#pragma unroll
        for (int t = 0; t < NT; t++) {
            float s1 = ls[t], s2 = ls2[t];
            s1 += __shfl_xor(s1, 16); s1 += __shfl_xor(s1, 32);
            s2 += __shfl_xor(s2, 16); s2 += __shfl_xor(s2, 32);
            if (quad == 0) {
                atomicAdd(&Ss[t * 16 + col], s1);
                atomicAdd(&Ss[FOUT + t * 16 + col], s2);
            }
        }
        __syncthreads();
        for (int i = threadIdx.x; i < 2 * FOUT; i += 256) atomicAdd(&stats[i], Ss[i]);
    }
}

// ================= layer-3 BN + segmented pool (batch sorted) =================
__global__ __launch_bounds__(256) void bn_pool_kernel(const float* __restrict__ y,
        const float* __restrict__ stats, const float* __restrict__ gw,
        const float* __restrict__ bw, const int* __restrict__ batch,
        float* __restrict__ pool, int N, float invN) {
    constexpr int F = 32, CH = 64;
    int q = threadIdx.x >> 5;
    int j = threadIdx.x & 31;
    int r0 = (blockIdx.x * 8 + q) * CH;
    if (r0 >= N) return;
    int r1 = min(r0 + CH, N);
    float mu = stats[j] * invN;
    float var = fmaxf(stats[F + j] * invN - mu * mu, 0.0f);
    float sc = rsqrtf(var + BN_EPS) * gw[j];
    float sh = bw[j] - mu * sc;
    int curg = batch[r0];
    float acc = 0.0f;
    for (int r = r0; r < r1; r++) {
        int g = batch[r];
        if (g != curg) {
            atomicAdd(pool + (size_t)curg * 32 + j, acc);
            acc = 0.0f;
            curg = g;
        }
        acc = fmaf(y[(size_t)r * 32 + j], sc, sh + acc);
    }
    atomicAdd(pool + (size_t)curg * 32 + j, acc);
}

// ================= FC head =================
__global__ __launch_bounds__(128) void fc_kernel(const float* __restrict__ pool,
        const float* __restrict__ Wf1, const float* __restrict__ bf1,
        const float* __restrict__ Wf2, const float* __restrict__ bf2,
        const float* __restrict__ Wf3, const float* __restrict__ bf3,
        float* __restrict__ out) {
    __shared__ float zin[32];
    __shared__ float h1[128];
    __shared__ float h2[64];
    const int gidx = blockIdx.x;
    const int t = threadIdx.x;
    if (t < 32) zin[t] = pool[(size_t)gidx * 32 + t];
    __syncthreads();
    {
        float a = bf1[t];
        for (int k = 0; k < 32; k++) a = fmaf(zin[k], Wf1[k * 128 + t], a);
        h1[t] = fmaxf(a, 0.0f);
    }
    __syncthreads();
    if (t < 64) {
        float a = bf2[t];
        for (int k = 0; k < 128; k++) a = fmaf(h1[k], Wf2[k * 64 + t], a);
        h2[t] = fmaxf(a, 0.0f);
    }
    __syncthreads();
    if (t < 10) {
        float a = bf3[t];
        for (int k = 0; k < 64; k++) a = fmaf(h2[k], Wf3[k * 10 + t], a);
        out[(size_t)gidx * 10 + t] = a;
    }
}

extern "C" void kernel_launch(void* const* d_in, const int* in_sizes, int n_in,
                              void* d_out, int out_size, void* d_ws, size_t ws_size,
                              hipStream_t stream) {
    const float* x   = (const float*)d_in[0];
    const int*  ei   = (const int*)d_in[1];
    const int*  batch= (const int*)d_in[2];
    const float* W1a = (const float*)d_in[3];  const float* b1a = (const float*)d_in[4];
    const float* W1b = (const float*)d_in[5];  const float* b1b = (const float*)d_in[6];
    const float* g1  = (const float*)d_in[7];  const float* be1 = (const float*)d_in[8];
    const float* W2a = (const float*)d_in[9];  const float* b2a = (const float*)d_in[10];
    const float* W2b = (const float*)d_in[11]; const float* b2b = (const float*)d_in[12];
    const float* g2  = (const float*)d_in[13]; const float* be2 = (const float*)d_in[14];
    const float* W3a = (const float*)d_in[15]; const float* b3a = (const float*)d_in[16];
    const float* W3b = (const float*)d_in[17]; const float* b3b = (const float*)d_in[18];
    const float* g3  = (const float*)d_in[19]; const float* be3 = (const float*)d_in[20];
    const float* Wf1 = (const float*)d_in[21]; const float* bf1 = (const float*)d_in[22];
    const float* Wf2 = (const float*)d_in[23]; const float* bf2 = (const float*)d_in[24];
    const float* Wf3 = (const float*)d_in[25]; const float* bf3 = (const float*)d_in[26];

    const int N = in_sizes[2];
    const int E = in_sizes[1] / 2;
    const int G = out_size / 10;
    const int* src = ei;
    const int* dst = ei + E;

    // ---- dedicated ws regions ----
    float* B0   = (float*)d_ws;              // N*128 f32 worth (= N*256 f16)
    float* B1   = B0 + (size_t)N * 128;
    float* pool = B1 + (size_t)N * 128;      // G*32
    float* st1  = pool + (size_t)G * 32;     // 256 each
    float* st2  = st1 + 256;
    float* st3  = st2 + 256;
    int* off    = (int*)(st3 + 256);         // N+1
    int* bsum   = off + (N + 1);             // 128
    int* elist  = bsum + 128;                // E
    float* v2   = (float*)(elist + E);       // 64
    float* v3   = v2 + 64;                   // 32

    // ---- aliases (stream-order safe) ----
    int* deg8  = (int*)B1;                    // 8*N ints (CSR phase)
    int* rank  = (int*)B1 + (size_t)8 * N;    // E ints   (CSR phase)
    int* deg   = rank + E;                    // N ints   (CSR phase)
    f16* xh    = (f16*)B0;                    // N*64  [B0 slot A: 0..N*64)
    f16* A1    = (f16*)B1;                    // N*64  [B1 slot A] (deg8/rank dead)
    f16* H1    = (f16*)B0 + (size_t)N * 64;   // N*128 [B0 slot B: N*64..N*192)
    f16* Y1    = (f16*)B1 + (size_t)N * 64;   // N*128 [B1 slot B]
    f16* Z1    = (f16*)B0;                    // N*64  [B0 slot A] (xh dead)
    f16* H2    = (f16*)B1;                    // N*64  [B1 slot A] (A1 dead)
    f16* Y2    = (f16*)B0 + (size_t)N * 64;   // N*64  [B0 slot B] (H1 dead)
    f16* Z2    = (f16*)B0;                    // N*32  [B0 slot A] (Z1 dead)
    f16* H3    = (f16*)B1;                    // N*32  [B1 slot A] (H2 dead)
    float* Y3  = B1 + (size_t)N * 64;         // N*32 f32 [B1 slot B] (Y1 dead)

    hipMemsetAsync(pool, 0, ((size_t)G * 32 + 768) * sizeof(float), stream);
    hipMemsetAsync(deg8, 0, (size_t)8 * N * sizeof(int), stream);

    const float invN = 1.0f / (float)N;
    const int NB = (N + 1023) / 1024;
    const int GG = 640;

    // ---- x -> f16 ----
    conv_kernel<<<(N * 16 + 255) / 256, 256, 0, stream>>>((const float4*)x, (f16x4*)xh, N * 16);

    // ---- CSR build ----
    hist_kernel<<<(E + 255) / 256, 256, 0, stream>>>(dst, deg8, rank, N, E);
    combine_kernel<<<(N + 255) / 256, 256, 0, stream>>>(deg8, deg, N);
    scan_block<<<NB, 1024, 0, stream>>>(deg, off, bsum, N);
    scan_bsum<<<1, 128, 0, stream>>>(bsum, NB);
    scan_finish<<<NB, 1024, 0, stream>>>(off, bsum, N);
    fill_kernel<<<(E + 255) / 256, 256, 0, stream>>>(src, dst, rank, off, deg8, elist, N, E);

    // ---- Layer 1: gather(x,64) -> gemm 64->128 relu -> gemm 128->128 relu+stats
    gather_v<64, false><<<(N + 31) / 32, 256, 0, stream>>>(off, elist, xh, A1, nullptr, nullptr, N);
    gemm_mfma<64, 128, false, true, true, false, f16><<<GG, 256, 0, stream>>>(A1, W1a, b1a, H1, nullptr, nullptr, nullptr, invN, N);
    gemm_mfma<128, 128, true, true, true, false, f16><<<GG, 256, 0, stream>>>(H1, W1b, b1b, Y1, st1, nullptr, nullptr, invN, N);

    // ---- Layer 2 (commuted): Z1 = Y1 @ diag(sc1) W2a; gather(Z1,64)+affine+relu -> H2
    prep_kernel<<<1, 64, 0, stream>>>(W2a, st1, g1, be1, v2, 128, 64, invN);
    gemm_mfma<128, 64, false, false, false, true, f16><<<GG, 256, 0, stream>>>(Y1, W2a, nullptr, Z1, nullptr, st1, g1, invN, N);
    gather_v<64, true><<<(N + 31) / 32, 256, 0, stream>>>(off, elist, Z1, H2, v2, b2a, N);
    gemm_mfma<64, 64, true, true, true, false, f16><<<GG, 256, 0, stream>>>(H2, W2b, b2b, Y2, st2, nullptr, nullptr, invN, N);

    // ---- Layer 3 (commuted): Z2 = Y2 @ diag(sc2) W3a; gather(Z2,32)+affine+relu -> H3
    prep_kernel<<<1, 64, 0, stream>>>(W3a, st2, g2, be2, v3, 64, 32, invN);
    gemm_mfma<64, 32, false, false, false, true, f16><<<GG, 256, 0, stream>>>(Y2, W3a, nullptr, Z2, nullptr, st2, g2, invN, N);
    gather_v<32, true><<<(N + 63) / 64, 256, 0, stream>>>(off, elist, Z2, H3, v3, b3a, N);
    gemm_mfma<32, 32, true, true, true, false, float><<<GG, 256, 0, stream>>>(H3, W3b, b3b, Y3, st3, nullptr, nullptr, invN, N);

    // ---- BN3 + segmented pool ----
    bn_pool_kernel<<<(N + 511) / 512, 256, 0, stream>>>(Y3, st3, g3, be3, batch, pool, N, invN);

    // ---- pooled MLP head ----
    fc_kernel<<<G, 128, 0, stream>>>(pool, Wf1, bf1, Wf2, bf2, Wf3, bf3, (float*)d_out);
}

// Round 8
// 658.973 us; speedup vs baseline: 1.0753x; 1.0753x over previous
//
#include <hip/hip_runtime.h>

#define BN_EPS 1e-5f

typedef _Float16 f16;
typedef _Float16 f16x8 __attribute__((ext_vector_type(8)));
typedef _Float16 f16x4 __attribute__((ext_vector_type(4)));
typedef float f32x4 __attribute__((ext_vector_type(4)));

#define NBLK 512      // blocks in bucket count/scatter passes
#define BSHIFT 10     // bucket = dst >> 10  (1024 nodes/bucket)

// ================= x -> f16 convert =================
__global__ __launch_bounds__(256) void conv_kernel(const float4* __restrict__ in,
        f16x4* __restrict__ out, int n4) {
    int i = blockIdx.x * 256 + threadIdx.x;
    if (i < n4) {
        float4 v = in[i];
        f16x4 o;
        o.x = (f16)v.x; o.y = (f16)v.y; o.z = (f16)v.z; o.w = (f16)v.w;
        out[i] = o;
    }
}

// ============ CSR build, bucketed: NO per-edge global atomics ============
// pass1: per-block LDS bucket histogram -> hist[b*NBLK + blk]
__global__ __launch_bounds__(256) void bkt_count(const int* __restrict__ dst,
        int* __restrict__ hist, int NBK, int CHUNK, int E) {
    __shared__ int lh[128];
    const int blk = blockIdx.x, t = threadIdx.x;
    for (int r = t; r < 128; r += 256) lh[r] = 0;
    __syncthreads();
    const int e0 = blk * CHUNK, e1 = min(E, e0 + CHUNK);
    for (int e = e0 + t; e < e1; e += 256) atomicAdd(&lh[dst[e] >> BSHIFT], 1);
    __syncthreads();
    for (int r = t; r < NBK; r += 256) hist[r * NBLK + blk] = lh[r];
}

// per-bucket exclusive scan over blocks; emit bucket totals
__global__ __launch_bounds__(512) void bkt_bscan(int* __restrict__ hist,
        int* __restrict__ btot) {
    __shared__ int sh[512];
    const int b = blockIdx.x, t = threadIdx.x;
    int v = hist[b * NBLK + t];
    sh[t] = v;
    __syncthreads();
    for (int d = 1; d < 512; d <<= 1) {
        int u = (t >= d) ? sh[t - d] : 0;
        __syncthreads();
        sh[t] += u;
        __syncthreads();
    }
    hist[b * NBLK + t] = sh[t] - v;        // exclusive
    if (t == 511) btot[b] = sh[511];
}

// scan bucket totals -> boff; also off[N] = E
__global__ __launch_bounds__(128) void bkt_boff(const int* __restrict__ btot,
        int* __restrict__ boff, int* __restrict__ off, int NBK, int N, int E) {
    __shared__ int sh[128];
    const int t = threadIdx.x;
    int v = (t < NBK) ? btot[t] : 0;
    sh[t] = v;
    __syncthreads();
    for (int d = 1; d < 128; d <<= 1) {
        int u = (t >= d) ? sh[t - d] : 0;
        __syncthreads();
        sh[t] += u;
        __syncthreads();
    }
    if (t < NBK) boff[t] = sh[t] - v;      // exclusive
    if (t == 0) { boff[NBK] = E; off[N] = E; }
}

// pass3: scatter (src,dst) into bucket-contiguous regions via LDS cursors
__global__ __launch_bounds__(256) void bkt_scatter(const int* __restrict__ src,
        const int* __restrict__ dst, const int* __restrict__ hist,
        const int* __restrict__ boff, int2* __restrict__ bucketed,
        int NBK, int CHUNK, int E) {
    __shared__ int lc[128];
    const int blk = blockIdx.x, t = threadIdx.x;
    for (int r = t; r < NBK; r += 256) lc[r] = boff[r] + hist[r * NBLK + blk];
    __syncthreads();
    const int e0 = blk * CHUNK, e1 = min(E, e0 + CHUNK);
    for (int e = e0 + t; e < e1; e += 256) {
        int d = dst[e];
        int slot = atomicAdd(&lc[d >> BSHIFT], 1);
        bucketed[slot] = make_int2(src[e], d);
    }
}

// pass4: per-bucket CSR finalize: local hist -> scan -> off[] + ranked elist
__global__ __launch_bounds__(256) void bkt_csr(const int2* __restrict__ bucketed,
        const int* __restrict__ boff, int* __restrict__ off,
        int* __restrict__ elist, int N) {
    __shared__ int lh[1024];
    __shared__ int lc[1024];
    __shared__ int ts[256];
    const int b = blockIdx.x, t = threadIdx.x;
    const int b0 = b << BSHIFT;
    const int R = min(N - b0, 1024);
    const int base = boff[b], cnt = boff[b + 1] - base;
    for (int r = t; r < 1024; r += 256) lh[r] = 0;
    __syncthreads();
    for (int i = t; i < cnt; i += 256) atomicAdd(&lh[bucketed[base + i].y - b0], 1);
    __syncthreads();
    // two-level exclusive scan of lh[1024]
    int s = 0;
#pragma unroll
    for (int u = 0; u < 4; u++) { int x = lh[t * 4 + u]; lh[t * 4 + u] = s; s += x; }
    ts[t] = s;
    __syncthreads();
    for (int d = 1; d < 256; d <<= 1) {
        int u = (t >= d) ? ts[t - d] : 0;
        __syncthreads();
        ts[t] += u;
        __syncthreads();
    }
    int ex = ts[t] - s;
#pragma unroll
    for (int u = 0; u < 4; u++) lh[t * 4 + u] += ex;
    __syncthreads();
    for (int r = t; r < R; r += 256) off[b0 + r] = base + lh[r];
    for (int r = t; r < 1024; r += 256) lc[r] = lh[r];
    __syncthreads();
    for (int i = t; i < cnt; i += 256) {
        int2 e = bucketed[base + i];
        int rk = atomicAdd(&lc[e.y - b0], 1);
        elist[base + rk] = e.x;
    }
}

// ================= vectorized gather (f16x8 = 16B per lane) ===================
// AFFINE==false: out[i] = in[i] + sum_{s in nbrs} in[s]
// AFFINE==true : out[i] = relu( acc + cnt*v + b ),  cnt = deg+1
template<int F, bool AFFINE>
__global__ __launch_bounds__(256) void gather_v(const int* __restrict__ off,
        const int* __restrict__ elist, const f16* __restrict__ in,
        f16* __restrict__ out, const float* __restrict__ v,
        const float* __restrict__ bias, int N) {
    constexpr int TPN = F / 8;           // threads per node
    constexpr int NPB = 256 / TPN;       // nodes per block
    const int i = blockIdx.x * NPB + threadIdx.x / TPN;
    const int l = threadIdx.x & (TPN - 1);
    if (i >= N) return;
    const int j0 = l * 8;
    f16x8 s = ((const f16x8*)(in + (size_t)i * F))[l];
    float a[8];
#pragma unroll
    for (int u = 0; u < 8; u++) a[u] = (float)s[u];
    int k = off[i], e = off[i + 1];
    const float cnt = (float)(e - k + 1);
    for (; k + 4 <= e; k += 4) {
        int n0 = elist[k], n1 = elist[k + 1], n2 = elist[k + 2], n3 = elist[k + 3];
        f16x8 p0 = ((const f16x8*)(in + (size_t)n0 * F))[l];
        f16x8 p1 = ((const f16x8*)(in + (size_t)n1 * F))[l];
        f16x8 p2 = ((const f16x8*)(in + (size_t)n2 * F))[l];
        f16x8 p3 = ((const f16x8*)(in + (size_t)n3 * F))[l];
#pragma unroll
        for (int u = 0; u < 8; u++)
            a[u] += ((float)p0[u] + (float)p1[u]) + ((float)p2[u] + (float)p3[u]);
    }
    for (; k < e; k++) {
        f16x8 p = ((const f16x8*)(in + (size_t)elist[k] * F))[l];
#pragma unroll
        for (int u = 0; u < 8; u++) a[u] += (float)p[u];
    }
    if (AFFINE) {
        float4 vv0 = *(const float4*)(v + j0);
        float4 vv1 = *(const float4*)(v + j0 + 4);
        float4 bb0 = *(const float4*)(bias + j0);
        float4 bb1 = *(const float4*)(bias + j0 + 4);
        a[0] = fmaxf(fmaf(cnt, vv0.x, a[0] + bb0.x), 0.0f);
        a[1] = fmaxf(fmaf(cnt, vv0.y, a[1] + bb0.y), 0.0f);
        a[2] = fmaxf(fmaf(cnt, vv0.z, a[2] + bb0.z), 0.0f);
        a[3] = fmaxf(fmaf(cnt, vv0.w, a[3] + bb0.w), 0.0f);
        a[4] = fmaxf(fmaf(cnt, vv1.x, a[4] + bb1.x), 0.0f);
        a[5] = fmaxf(fmaf(cnt, vv1.y, a[5] + bb1.y), 0.0f);
        a[6] = fmaxf(fmaf(cnt, vv1.z, a[6] + bb1.z), 0.0f);
        a[7] = fmaxf(fmaf(cnt, vv1.w, a[7] + bb1.w), 0.0f);
    }
    f16x8 o;
#pragma unroll
    for (int u = 0; u < 8; u++) o[u] = (f16)a[u];
    ((f16x8*)(out + (size_t)i * F))[l] = o;
}

// ================= prep: v[j] = sum_k sh[k] * W[k][j] =========================
__global__ __launch_bounds__(64) void prep_kernel(const float* __restrict__ W,
        const float* __restrict__ stats, const float* __restrict__ g,
        const float* __restrict__ be, float* __restrict__ v,
        int FIN, int FOUT, float invN) {
    int j = threadIdx.x;
    if (j >= FOUT) return;
    float acc = 0.0f;
    for (int k = 0; k < FIN; k++) {
        float mu = stats[k] * invN;
        float var = fmaxf(stats[FIN + k] * invN - mu * mu, 0.0f);
        float sc = rsqrtf(var + BN_EPS) * g[k];
        float sh = be[k] - mu * sc;
        acc = fmaf(sh, W[(size_t)k * FOUT + j], acc);
    }
    v[j] = acc;
}

// ================= MFMA GEMM ==================================================
template<int FIN, int FOUT, bool STATS, bool RELU, bool BIAS, bool BNW, typename OutT>
__global__ __launch_bounds__(256) void gemm_mfma(const f16* __restrict__ A,
        const float* __restrict__ W, const float* __restrict__ bias,
        OutT* __restrict__ Out, float* __restrict__ stats,
        const float* __restrict__ bnstats, const float* __restrict__ bng,
        float invN, int N) {
    constexpr int NS = FIN / 32;    // k-steps
    constexpr int NT = FOUT / 16;   // n-tiles
    __shared__ f16 Wl[NS * NT * 512];
    __shared__ float Bl[BIAS ? FOUT : 1];
    __shared__ float Ss[STATS ? 2 * FOUT : 1];
    __shared__ float Scs[BNW ? FIN : 1];

    if (BNW) {
        for (int k = threadIdx.x; k < FIN; k += 256) {
            float mu = bnstats[k] * invN;
            float var = fmaxf(bnstats[FIN + k] * invN - mu * mu, 0.0f);
            Scs[k] = rsqrtf(var + BN_EPS) * bng[k];
        }
        __syncthreads();
    }
    for (int i = threadIdx.x; i < FIN * FOUT; i += 256) {
        int k = i / FOUT, n = i & (FOUT - 1);
        int s = k >> 5, kk = k & 31;
        int lane = (n & 15) | ((kk >> 3) << 4);
        int j = kk & 7;
        float wv = W[i];
        if (BNW) wv *= Scs[k];
        Wl[(((s * NT) + (n >> 4)) << 9) + (lane << 3) + j] = (f16)wv;
    }
    if (BIAS && threadIdx.x < FOUT) Bl[threadIdx.x] = bias[threadIdx.x];
    if (STATS) for (int i = threadIdx.x; i < 2 * FOUT; i += 256) Ss[i] = 0.0f;
    __syncthreads();

    const int wid = threadIdx.x >> 6;
    const int lane = threadIdx.x & 63;
    const int col = lane & 15;
    const int quad = lane >> 4;

    f16x8 Bf[NS][NT];
#pragma unroll
    for (int s = 0; s < NS; s++)
#pragma unroll
        for (int t = 0; t < NT; t++)
            Bf[s][t] = *(const f16x8*)&Wl[((s * NT + t) << 9) + (lane << 3)];

    float ls[NT], ls2[NT];
#pragma unroll
    for (int t = 0; t < NT; t++) { ls[t] = 0.0f; ls2[t] = 0.0f; }

    const int S = N >> 4;
    for (int sidx = blockIdx.x * 4 + wid; sidx < S; sidx += (int)gridDim.x * 4) {
        const int m0 = sidx << 4;
        const f16* a0 = A + (size_t)(m0 + col) * FIN + (quad << 3);
        f16x8 Af[NS];
#pragma unroll
        for (int s = 0; s < NS; s++) Af[s] = *(const f16x8*)(a0 + s * 32);
        f32x4 acc[NT];
#pragma unroll
        for (int t = 0; t < NT; t++) {
            float b = BIAS ? Bl[t * 16 + col] : 0.0f;
            acc[t] = (f32x4){b, b, b, b};
        }
#pragma unroll
        for (int t = 0; t < NT; t++)
#pragma unroll
            for (int s = 0; s < NS; s++)
                acc[t] = __builtin_amdgcn_mfma_f32_16x16x32_f16(Af[s], Bf[s][t], acc[t], 0, 0, 0);
#pragma unroll
        for (int t = 0; t < NT; t++) {
            float v0 = acc[t][0], v1 = acc[t][1], v2 = acc[t][2], v3 = acc[t][3];
            if (RELU) {
                v0 = fmaxf(v0, 0.0f); v1 = fmaxf(v1, 0.0f);
                v2 = fmaxf(v2, 0.0f); v3 = fmaxf(v3, 0.0f);
            }
            if (STATS) {
                ls[t]  += (v0 + v1) + (v2 + v3);
                ls2[t] += (v0 * v0 + v1 * v1) + (v2 * v2 + v3 * v3);
            }
            OutT* o = Out + (size_t)(m0 + quad * 4) * FOUT + t * 16 + col;
            o[0]        = (OutT)v0;
            o[FOUT]     = (OutT)v1;
            o[2 * FOUT] = (OutT)v2;
            o[3 * FOUT] = (OutT)v3;
        }
    }

    if (STATS) {
#pragma unroll
        for (int t = 0; t < NT; t++) {
            float s1 = ls[t], s2 = ls2[t];
            s1 += __shfl_xor(s1, 16); s1 += __shfl_xor(s1, 32);
            s2 += __shfl_xor(s2, 16); s2 += __shfl_xor(s2, 32);
            if (quad == 0) {
                atomicAdd(&Ss[t * 16 + col], s1);
                atomicAdd(&Ss[FOUT + t * 16 + col], s2);
            }
        }
        __syncthreads();
        for (int i = threadIdx.x; i < 2 * FOUT; i += 256) atomicAdd(&stats[i], Ss[i]);
    }
}

// ================= layer-3 BN + segmented pool (batch sorted) =================
__global__ __launch_bounds__(256) void bn_pool_kernel(const float* __restrict__ y,
        const float* __restrict__ stats, const float* __restrict__ gw,
        const float* __restrict__ bw, const int* __restrict__ batch,
        float* __restrict__ pool, int N, float invN) {
    constexpr int F = 32, CH = 64;
    int q = threadIdx.x >> 5;
    int j = threadIdx.x & 31;
    int r0 = (blockIdx.x * 8 + q) * CH;
    if (r0 >= N) return;
    int r1 = min(r0 + CH, N);
    float mu = stats[j] * invN;
    float var = fmaxf(stats[F + j] * invN - mu * mu, 0.0f);
    float sc = rsqrtf(var + BN_EPS) * gw[j];
    float sh = bw[j] - mu * sc;
    int curg = batch[r0];
    float acc = 0.0f;
    for (int r = r0; r < r1; r++) {
        int g = batch[r];
        if (g != curg) {
            atomicAdd(pool + (size_t)curg * 32 + j, acc);
            acc = 0.0f;
            curg = g;
        }
        acc = fmaf(y[(size_t)r * 32 + j], sc, sh + acc);
    }
    atomicAdd(pool + (size_t)curg * 32 + j, acc);
}

// ================= FC head =================
__global__ __launch_bounds__(128) void fc_kernel(const float* __restrict__ pool,
        const float* __restrict__ Wf1, const float* __restrict__ bf1,
        const float* __restrict__ Wf2, const float* __restrict__ bf2,
        const float* __restrict__ Wf3, const float* __restrict__ bf3,
        float* __restrict__ out) {
    __shared__ float zin[32];
    __shared__ float h1[128];
    __shared__ float h2[64];
    const int gidx = blockIdx.x;
    const int t = threadIdx.x;
    if (t < 32) zin[t] = pool[(size_t)gidx * 32 + t];
    __syncthreads();
    {
        float a = bf1[t];
        for (int k = 0; k < 32; k++) a = fmaf(zin[k], Wf1[k * 128 + t], a);
        h1[t] = fmaxf(a, 0.0f);
    }
    __syncthreads();
    if (t < 64) {
        float a = bf2[t];
        for (int k = 0; k < 128; k++) a = fmaf(h1[k], Wf2[k * 64 + t], a);
        h2[t] = fmaxf(a, 0.0f);
    }
    __syncthreads();
    if (t < 10) {
        float a = bf3[t];
        for (int k = 0; k < 64; k++) a = fmaf(h2[k], Wf3[k * 10 + t], a);
        out[(size_t)gidx * 10 + t] = a;
    }
}

extern "C" void kernel_launch(void* const* d_in, const int* in_sizes, int n_in,
                              void* d_out, int out_size, void* d_ws, size_t ws_size,
                              hipStream_t stream) {
    const float* x   = (const float*)d_in[0];
    const int*  ei   = (const int*)d_in[1];
    const int*  batch= (const int*)d_in[2];
    const float* W1a = (const float*)d_in[3];  const float* b1a = (const float*)d_in[4];
    const float* W1b = (const float*)d_in[5];  const float* b1b = (const float*)d_in[6];
    const float* g1  = (const float*)d_in[7];  const float* be1 = (const float*)d_in[8];
    const float* W2a = (const float*)d_in[9];  const float* b2a = (const float*)d_in[10];
    const float* W2b = (const float*)d_in[11]; const float* b2b = (const float*)d_in[12];
    const float* g2  = (const float*)d_in[13]; const float* be2 = (const float*)d_in[14];
    const float* W3a = (const float*)d_in[15]; const float* b3a = (const float*)d_in[16];
    const float* W3b = (const float*)d_in[17]; const float* b3b = (const float*)d_in[18];
    const float* g3  = (const float*)d_in[19]; const float* be3 = (const float*)d_in[20];
    const float* Wf1 = (const float*)d_in[21]; const float* bf1 = (const float*)d_in[22];
    const float* Wf2 = (const float*)d_in[23]; const float* bf2 = (const float*)d_in[24];
    const float* Wf3 = (const float*)d_in[25]; const float* bf3 = (const float*)d_in[26];

    const int N = in_sizes[2];
    const int E = in_sizes[1] / 2;
    const int G = out_size / 10;
    const int* src = ei;
    const int* dst = ei + E;

    const int NBK = (N + 1023) >> BSHIFT;        // buckets (98 for N=100K)
    const int CHUNK = (E + NBLK - 1) / NBLK;

    // ---- dedicated ws regions ----
    float* B0   = (float*)d_ws;              // N*128 f32 worth (= N*256 f16)
    float* B1   = B0 + (size_t)N * 128;
    float* pool = B1 + (size_t)N * 128;      // G*32
    float* st1  = pool + (size_t)G * 32;     // 256 each
    float* st2  = st1 + 256;
    float* st3  = st2 + 256;
    int* off    = (int*)(st3 + 256);         // N+1
    int* elist  = off + (N + 1);             // E
    float* v2   = (float*)(elist + E);       // 64
    float* v3   = v2 + 64;                   // 32
    int* boff   = (int*)(v3 + 32);           // NBK+1
    int* btot   = boff + (NBK + 1);          // NBK

    // ---- CSR-phase aliases in B1 (dead before B1's activation use) ----
    int2* bucketed = (int2*)B1;              // E int2 (25.6 MB)
    int*  hist     = (int*)(bucketed + E);   // NBK*NBLK (200 KB)

    // ---- activation aliases (stream-order safe) ----
    f16* xh    = (f16*)B0;                    // N*64  [B0 slot A]
    f16* A1    = (f16*)B1;                    // N*64  [B1 slot A] (bucketed dead)
    f16* H1    = (f16*)B0 + (size_t)N * 64;   // N*128 [B0 slot B]
    f16* Y1    = (f16*)B1 + (size_t)N * 64;   // N*128 [B1 slot B] (hist dead)
    f16* Z1    = (f16*)B0;                    // N*64  [B0 slot A] (xh dead)
    f16* H2    = (f16*)B1;                    // N*64  [B1 slot A] (A1 dead)
    f16* Y2    = (f16*)B0 + (size_t)N * 64;   // N*64  [B0 slot B] (H1 dead)
    f16* Z2    = (f16*)B0;                    // N*32  [B0 slot A] (Z1 dead)
    f16* H3    = (f16*)B1;                    // N*32  [B1 slot A] (H2 dead)
    float* Y3  = B1 + (size_t)N * 64;         // N*32 f32 [B1 slot B] (Y1 dead)

    hipMemsetAsync(pool, 0, ((size_t)G * 32 + 768) * sizeof(float), stream);

    const float invN = 1.0f / (float)N;
    const int GG = 640;

    // ---- x -> f16 ----
    conv_kernel<<<(N * 16 + 255) / 256, 256, 0, stream>>>((const float4*)x, (f16x4*)xh, N * 16);

    // ---- CSR build (bucketed, LDS atomics only) ----
    bkt_count  <<<NBLK, 256, 0, stream>>>(dst, hist, NBK, CHUNK, E);
    bkt_bscan  <<<NBK, 512, 0, stream>>>(hist, btot);
    bkt_boff   <<<1, 128, 0, stream>>>(btot, boff, off, NBK, N, E);
    bkt_scatter<<<NBLK, 256, 0, stream>>>(src, dst, hist, boff, bucketed, NBK, CHUNK, E);
    bkt_csr    <<<NBK, 256, 0, stream>>>(bucketed, boff, off, elist, N);

    // ---- Layer 1: gather(x,64) -> gemm 64->128 relu -> gemm 128->128 relu+stats
    gather_v<64, false><<<(N + 31) / 32, 256, 0, stream>>>(off, elist, xh, A1, nullptr, nullptr, N);
    gemm_mfma<64, 128, false, true, true, false, f16><<<GG, 256, 0, stream>>>(A1, W1a, b1a, H1, nullptr, nullptr, nullptr, invN, N);
    gemm_mfma<128, 128, true, true, true, false, f16><<<GG, 256, 0, stream>>>(H1, W1b, b1b, Y1, st1, nullptr, nullptr, invN, N);

    // ---- Layer 2 (commuted): Z1 = Y1 @ diag(sc1) W2a; gather+affine+relu -> H2
    prep_kernel<<<1, 64, 0, stream>>>(W2a, st1, g1, be1, v2, 128, 64, invN);
    gemm_mfma<128, 64, false, false, false, true, f16><<<GG, 256, 0, stream>>>(Y1, W2a, nullptr, Z1, nullptr, st1, g1, invN, N);
    gather_v<64, true><<<(N + 31) / 32, 256, 0, stream>>>(off, elist, Z1, H2, v2, b2a, N);
    gemm_mfma<64, 64, true, true, true, false, f16><<<GG, 256, 0, stream>>>(H2, W2b, b2b, Y2, st2, nullptr, nullptr, invN, N);

    // ---- Layer 3 (commuted): Z2 = Y2 @ diag(sc2) W3a; gather+affine+relu -> H3
    prep_kernel<<<1, 64, 0, stream>>>(W3a, st2, g2, be2, v3, 64, 32, invN);
    gemm_mfma<64, 32, false, false, false, true, f16><<<GG, 256, 0, stream>>>(Y2, W3a, nullptr, Z2, nullptr, st2, g2, invN, N);
    gather_v<32, true><<<(N + 63) / 64, 256, 0, stream>>>(off, elist, Z2, H3, v3, b3a, N);
    gemm_mfma<32, 32, true, true, true, false, float><<<GG, 256, 0, stream>>>(H3, W3b, b3b, Y3, st3, nullptr, nullptr, invN, N);

    // ---- BN3 + segmented pool ----
    bn_pool_kernel<<<(N + 511) / 512, 256, 0, stream>>>(Y3, st3, g3, be3, batch, pool, N, invN);

    // ---- pooled MLP head ----
    fc_kernel<<<G, 128, 0, stream>>>(pool, Wf1, bf1, Wf2, bf2, Wf3, bf3, (float*)d_out);
}

// Round 9
// 553.922 us; speedup vs baseline: 1.2793x; 1.1896x over previous
//
#include <hip/hip_runtime.h>

#define BN_EPS 1e-5f

typedef _Float16 f16;
typedef _Float16 f16x8 __attribute__((ext_vector_type(8)));
typedef _Float16 f16x4 __attribute__((ext_vector_type(4)));
typedef float f32x4 __attribute__((ext_vector_type(4)));

#define NBLK 512      // blocks in bucket count/scatter passes
#define BSHIFT 8      // bucket = dst >> 8  (256 nodes/bucket)
#define BMASK 255

// ================= x -> f16 convert =================
__global__ __launch_bounds__(256) void conv_kernel(const float4* __restrict__ in,
        f16x4* __restrict__ out, int n4) {
    int i = blockIdx.x * 256 + threadIdx.x;
    if (i < n4) {
        float4 v = in[i];
        f16x4 o;
        o.x = (f16)v.x; o.y = (f16)v.y; o.z = (f16)v.z; o.w = (f16)v.w;
        out[i] = o;
    }
}

// ============ CSR build, bucketed: NO per-edge global atomics ============
// pass1: per-block LDS bucket histogram -> hist[b*NBLK + blk]
__global__ __launch_bounds__(256) void bkt_count(const int* __restrict__ dst,
        int* __restrict__ hist, int NBK, int CHUNK, int E) {
    __shared__ int lh[512];
    const int blk = blockIdx.x, t = threadIdx.x;
    for (int r = t; r < 512; r += 256) lh[r] = 0;
    __syncthreads();
    const int e0 = blk * CHUNK, e1 = min(E, e0 + CHUNK);
    for (int e = e0 + t; e < e1; e += 256) atomicAdd(&lh[dst[e] >> BSHIFT], 1);
    __syncthreads();
    for (int r = t; r < NBK; r += 256) hist[r * NBLK + blk] = lh[r];
}

// per-bucket exclusive scan over blocks; emit bucket totals
__global__ __launch_bounds__(512) void bkt_bscan(int* __restrict__ hist,
        int* __restrict__ btot) {
    __shared__ int sh[512];
    const int b = blockIdx.x, t = threadIdx.x;
    int v = hist[b * NBLK + t];
    sh[t] = v;
    __syncthreads();
    for (int d = 1; d < 512; d <<= 1) {
        int u = (t >= d) ? sh[t - d] : 0;
        __syncthreads();
        sh[t] += u;
        __syncthreads();
    }
    hist[b * NBLK + t] = sh[t] - v;        // exclusive
    if (t == 511) btot[b] = sh[511];
}

// scan bucket totals -> boff; also off[N] = E
__global__ __launch_bounds__(512) void bkt_boff(const int* __restrict__ btot,
        int* __restrict__ boff, int* __restrict__ off, int NBK, int N, int E) {
    __shared__ int sh[512];
    const int t = threadIdx.x;
    int v = (t < NBK) ? btot[t] : 0;
    sh[t] = v;
    __syncthreads();
    for (int d = 1; d < 512; d <<= 1) {
        int u = (t >= d) ? sh[t - d] : 0;
        __syncthreads();
        sh[t] += u;
        __syncthreads();
    }
    if (t < NBK) boff[t] = sh[t] - v;      // exclusive
    if (t == 0) { boff[NBK] = E; off[N] = E; }
}

// pass3: scatter packed (local_dst<<18 | src) into bucket regions (LDS cursors)
__global__ __launch_bounds__(256) void bkt_scatter(const int* __restrict__ src,
        const int* __restrict__ dst, const int* __restrict__ hist,
        const int* __restrict__ boff, int* __restrict__ bucketed,
        int NBK, int CHUNK, int E) {
    __shared__ int lc[512];
    const int blk = blockIdx.x, t = threadIdx.x;
    for (int r = t; r < NBK; r += 256) lc[r] = boff[r] + hist[r * NBLK + blk];
    __syncthreads();
    const int e0 = blk * CHUNK, e1 = min(E, e0 + CHUNK);
    for (int e = e0 + t; e < e1; e += 256) {
        int d = dst[e];
        int slot = atomicAdd(&lc[d >> BSHIFT], 1);
        bucketed[slot] = ((d & BMASK) << 18) | src[e];
    }
}

// pass4: per-bucket CSR finalize: local hist -> scan -> off[] + ranked elist
__global__ __launch_bounds__(512) void bkt_csr(const int* __restrict__ bucketed,
        const int* __restrict__ boff, int* __restrict__ off,
        int* __restrict__ elist, int N) {
    __shared__ int lh[256];
    __shared__ int lc[256];
    __shared__ int sh[256];
    const int b = blockIdx.x, t = threadIdx.x;
    const int b0 = b << BSHIFT;
    const int R = min(N - b0, 256);
    const int base = boff[b], cnt = boff[b + 1] - base;
    if (t < 256) lh[t] = 0;
    __syncthreads();
    for (int i = t; i < cnt; i += 512) atomicAdd(&lh[bucketed[base + i] >> 18], 1);
    __syncthreads();
    int v = 0;
    if (t < 256) { v = lh[t]; sh[t] = v; }
    __syncthreads();
    for (int d = 1; d < 256; d <<= 1) {
        int u = 0;
        if (t < 256 && t >= d) u = sh[t - d];
        __syncthreads();
        if (t < 256) sh[t] += u;
        __syncthreads();
    }
    if (t < 256) { int ex = sh[t] - v; lh[t] = ex; lc[t] = ex; }
    __syncthreads();
    if (t < R) off[b0 + t] = base + lh[t];
    for (int i = t; i < cnt; i += 512) {
        int p = bucketed[base + i];
        int rk = atomicAdd(&lc[p >> 18], 1);
        elist[base + rk] = p & 0x3FFFF;
    }
}

// ================= vectorized gather (f16x8 = 16B per lane) ===================
// AFFINE==false: out[i] = in[i] + sum_{s in nbrs} in[s]
// AFFINE==true : out[i] = relu( acc + cnt*v + b ),  cnt = deg+1
template<int F, bool AFFINE>
__global__ __launch_bounds__(256) void gather_v(const int* __restrict__ off,
        const int* __restrict__ elist, const f16* __restrict__ in,
        f16* __restrict__ out, const float* __restrict__ v,
        const float* __restrict__ bias, int N) {
    constexpr int TPN = F / 8;           // threads per node
    constexpr int NPB = 256 / TPN;       // nodes per block
    const int i = blockIdx.x * NPB + threadIdx.x / TPN;
    const int l = threadIdx.x & (TPN - 1);
    if (i >= N) return;
    const int j0 = l * 8;
    f16x8 s = ((const f16x8*)(in + (size_t)i * F))[l];
    float a[8];
#pragma unroll
    for (int u = 0; u < 8; u++) a[u] = (float)s[u];
    int k = off[i], e = off[i + 1];
    const float cnt = (float)(e - k + 1);
    for (; k + 4 <= e; k += 4) {
        int n0 = elist[k], n1 = elist[k + 1], n2 = elist[k + 2], n3 = elist[k + 3];
        f16x8 p0 = ((const f16x8*)(in + (size_t)n0 * F))[l];
        f16x8 p1 = ((const f16x8*)(in + (size_t)n1 * F))[l];
        f16x8 p2 = ((const f16x8*)(in + (size_t)n2 * F))[l];
        f16x8 p3 = ((const f16x8*)(in + (size_t)n3 * F))[l];
#pragma unroll
        for (int u = 0; u < 8; u++)
            a[u] += ((float)p0[u] + (float)p1[u]) + ((float)p2[u] + (float)p3[u]);
    }
    for (; k < e; k++) {
        f16x8 p = ((const f16x8*)(in + (size_t)elist[k] * F))[l];
#pragma unroll
        for (int u = 0; u < 8; u++) a[u] += (float)p[u];
    }
    if (AFFINE) {
        float4 vv0 = *(const float4*)(v + j0);
        float4 vv1 = *(const float4*)(v + j0 + 4);
        float4 bb0 = *(const float4*)(bias + j0);
        float4 bb1 = *(const float4*)(bias + j0 + 4);
        a[0] = fmaxf(fmaf(cnt, vv0.x, a[0] + bb0.x), 0.0f);
        a[1] = fmaxf(fmaf(cnt, vv0.y, a[1] + bb0.y), 0.0f);
        a[2] = fmaxf(fmaf(cnt, vv0.z, a[2] + bb0.z), 0.0f);
        a[3] = fmaxf(fmaf(cnt, vv0.w, a[3] + bb0.w), 0.0f);
        a[4] = fmaxf(fmaf(cnt, vv1.x, a[4] + bb1.x), 0.0f);
        a[5] = fmaxf(fmaf(cnt, vv1.y, a[5] + bb1.y), 0.0f);
        a[6] = fmaxf(fmaf(cnt, vv1.z, a[6] + bb1.z), 0.0f);
        a[7] = fmaxf(fmaf(cnt, vv1.w, a[7] + bb1.w), 0.0f);
    }
    f16x8 o;
#pragma unroll
    for (int u = 0; u < 8; u++) o[u] = (f16)a[u];
    ((f16x8*)(out + (size_t)i * F))[l] = o;
}

// ================= prep: v[j] = sum_k sh[k] * W[k][j] =========================
__global__ __launch_bounds__(64) void prep_kernel(const float* __restrict__ W,
        const float* __restrict__ stats, const float* __restrict__ g,
        const float* __restrict__ be, float* __restrict__ v,
        int FIN, int FOUT, float invN) {
    int j = threadIdx.x;
    if (j >= FOUT) return;
    float acc = 0.0f;
    for (int k = 0; k < FIN; k++) {
        float mu = stats[k] * invN;
        float var = fmaxf(stats[FIN + k] * invN - mu * mu, 0.0f);
        float sc = rsqrtf(var + BN_EPS) * g[k];
        float sh = be[k] - mu * sc;
        acc = fmaf(sh, W[(size_t)k * FOUT + j], acc);
    }
    v[j] = acc;
}

// ================= MFMA GEMM ==================================================
template<int FIN, int FOUT, bool STATS, bool RELU, bool BIAS, bool BNW, typename OutT>
__global__ __launch_bounds__(256) void gemm_mfma(const f16* __restrict__ A,
        const float* __restrict__ W, const float* __restrict__ bias,
        OutT* __restrict__ Out, float* __restrict__ stats,
        const float* __restrict__ bnstats, const float* __restrict__ bng,
        float invN, int N) {
    constexpr int NS = FIN / 32;    // k-steps
    constexpr int NT = FOUT / 16;   // n-tiles
    __shared__ f16 Wl[NS * NT * 512];
    __shared__ float Bl[BIAS ? FOUT : 1];
    __shared__ float Ss[STATS ? 2 * FOUT : 1];
    __shared__ float Scs[BNW ? FIN : 1];

    if (BNW) {
        for (int k = threadIdx.x; k < FIN; k += 256) {
            float mu = bnstats[k] * invN;
            float var = fmaxf(bnstats[FIN + k] * invN - mu * mu, 0.0f);
            Scs[k] = rsqrtf(var + BN_EPS) * bng[k];
        }
        __syncthreads();
    }
    for (int i = threadIdx.x; i < FIN * FOUT; i += 256) {
        int k = i / FOUT, n = i & (FOUT - 1);
        int s = k >> 5, kk = k & 31;
        int lane = (n & 15) | ((kk >> 3) << 4);
        int j = kk & 7;
        float wv = W[i];
        if (BNW) wv *= Scs[k];
        Wl[(((s * NT) + (n >> 4)) << 9) + (lane << 3) + j] = (f16)wv;
    }
    if (BIAS && threadIdx.x < FOUT) Bl[threadIdx.x] = bias[threadIdx.x];
    if (STATS) for (int i = threadIdx.x; i < 2 * FOUT; i += 256) Ss[i] = 0.0f;
    __syncthreads();

    const int wid = threadIdx.x >> 6;
    const int lane = threadIdx.x & 63;
    const int col = lane & 15;
    const int quad = lane >> 4;

    f16x8 Bf[NS][NT];
#pragma unroll
    for (int s = 0; s < NS; s++)
#pragma unroll
        for (int t = 0; t < NT; t++)
            Bf[s][t] = *(const f16x8*)&Wl[((s * NT + t) << 9) + (lane << 3)];

    float ls[NT], ls2[NT];
#pragma unroll
    for (int t = 0; t < NT; t++) { ls[t] = 0.0f; ls2[t] = 0.0f; }

    const int S = N >> 4;
    for (int sidx = blockIdx.x * 4 + wid; sidx < S; sidx += (int)gridDim.x * 4) {
        const int m0 = sidx << 4;
        const f16* a0 = A + (size_t)(m0 + col) * FIN + (quad << 3);
        f16x8 Af[NS];
#pragma unroll
        for (int s = 0; s < NS; s++) Af[s] = *(const f16x8*)(a0 + s * 32);
        f32x4 acc[NT];
#pragma unroll
        for (int t = 0; t < NT; t++) {
            float b = BIAS ? Bl[t * 16 + col] : 0.0f;
            acc[t] = (f32x4){b, b, b, b};
        }
#pragma unroll
        for (int t = 0; t < NT; t++)
#pragma unroll
            for (int s = 0; s < NS; s++)
                acc[t] = __builtin_amdgcn_mfma_f32_16x16x32_f16(Af[s], Bf[s][t], acc[t], 0, 0, 0);
#pragma unroll
        for (int t = 0; t < NT; t++) {
            float v0 = acc[t][0], v1 = acc[t][1], v2 = acc[t][2], v3 = acc[t][3];
            if (RELU) {
                v0 = fmaxf(v0, 0.0f); v1 = fmaxf(v1, 0.0f);
                v2 = fmaxf(v2, 0.0f); v3 = fmaxf(v3, 0.0f);
            }
            if (STATS) {
                ls[t]  += (v0 + v1) + (v2 + v3);
                ls2[t] += (v0 * v0 + v1 * v1) + (v2 * v2 + v3 * v3);
            }
            OutT* o = Out + (size_t)(m0 + quad * 4) * FOUT + t * 16 + col;
            o[0]        = (OutT)v0;
            o[FOUT]     = (OutT)v1;
            o[2 * FOUT] = (OutT)v2;
            o[3 * FOUT] = (OutT)v3;
        }
    }

    if (STATS) {
#pragma unroll
        for (int t = 0; t < NT; t++) {
            float s1 = ls[t], s2 = ls2[t];
            s1 += __shfl_xor(s1, 16); s1 += __shfl_xor(s1, 32);
            s2 += __shfl_xor(s2, 16); s2 += __shfl_xor(s2, 32);
            if (quad == 0) {
                atomicAdd(&Ss[t * 16 + col], s1);
                atomicAdd(&Ss[FOUT + t * 16 + col], s2);
            }
        }
        __syncthreads();
        for (int i = threadIdx.x; i < 2 * FOUT; i += 256) atomicAdd(&stats[i], Ss[i]);
    }
}

// ================= layer-3 BN + segmented pool (batch sorted) =================
__global__ __launch_bounds__(256) void bn_pool_kernel(const float* __restrict__ y,
        const float* __restrict__ stats, const float* __restrict__ gw,
        const float* __restrict__ bw, const int* __restrict__ batch,
        float* __restrict__ pool, int N, float invN) {
    constexpr int F = 32, CH = 64;
    int q = threadIdx.x >> 5;
    int j = threadIdx.x & 31;
    int r0 = (blockIdx.x * 8 + q) * CH;
    if (r0 >= N) return;
    int r1 = min(r0 + CH, N);
    float mu = stats[j] * invN;
    float var = fmaxf(stats[F + j] * invN - mu * mu, 0.0f);
    float sc = rsqrtf(var + BN_EPS) * gw[j];
    float sh = bw[j] - mu * sc;
    int curg = batch[r0];
    float acc = 0.0f;
    for (int r = r0; r < r1; r++) {
        int g = batch[r];
        if (g != curg) {
            atomicAdd(pool + (size_t)curg * 32 + j, acc);
            acc = 0.0f;
            curg = g;
        }
        acc = fmaf(y[(size_t)r * 32 + j], sc, sh + acc);
    }
    atomicAdd(pool + (size_t)curg * 32 + j, acc);
}

// ================= FC head =================
__global__ __launch_bounds__(128) void fc_kernel(const float* __restrict__ pool,
        const float* __restrict__ Wf1, const float* __restrict__ bf1,
        const float* __restrict__ Wf2, const float* __restrict__ bf2,
        const float* __restrict__ Wf3, const float* __restrict__ bf3,
        float* __restrict__ out) {
    __shared__ float zin[32];
    __shared__ float h1[128];
    __shared__ float h2[64];
    const int gidx = blockIdx.x;
    const int t = threadIdx.x;
    if (t < 32) zin[t] = pool[(size_t)gidx * 32 + t];
    __syncthreads();
    {
        float a = bf1[t];
        for (int k = 0; k < 32; k++) a = fmaf(zin[k], Wf1[k * 128 + t], a);
        h1[t] = fmaxf(a, 0.0f);
    }
    __syncthreads();
    if (t < 64) {
        float a = bf2[t];
        for (int k = 0; k < 128; k++) a = fmaf(h1[k], Wf2[k * 64 + t], a);
        h2[t] = fmaxf(a, 0.0f);
    }
    __syncthreads();
    if (t < 10) {
        float a = bf3[t];
        for (int k = 0; k < 64; k++) a = fmaf(h2[k], Wf3[k * 10 + t], a);
        out[(size_t)gidx * 10 + t] = a;
    }
}

extern "C" void kernel_launch(void* const* d_in, const int* in_sizes, int n_in,
                              void* d_out, int out_size, void* d_ws, size_t ws_size,
                              hipStream_t stream) {
    const float* x   = (const float*)d_in[0];
    const int*  ei   = (const int*)d_in[1];
    const int*  batch= (const int*)d_in[2];
    const float* W1a = (const float*)d_in[3];  const float* b1a = (const float*)d_in[4];
    const float* W1b = (const float*)d_in[5];  const float* b1b = (const float*)d_in[6];
    const float* g1  = (const float*)d_in[7];  const float* be1 = (const float*)d_in[8];
    const float* W2a = (const float*)d_in[9];  const float* b2a = (const float*)d_in[10];
    const float* W2b = (const float*)d_in[11]; const float* b2b = (const float*)d_in[12];
    const float* g2  = (const float*)d_in[13]; const float* be2 = (const float*)d_in[14];
    const float* W3a = (const float*)d_in[15]; const float* b3a = (const float*)d_in[16];
    const float* W3b = (const float*)d_in[17]; const float* b3b = (const float*)d_in[18];
    const float* g3  = (const float*)d_in[19]; const float* be3 = (const float*)d_in[20];
    const float* Wf1 = (const float*)d_in[21]; const float* bf1 = (const float*)d_in[22];
    const float* Wf2 = (const float*)d_in[23]; const float* bf2 = (const float*)d_in[24];
    const float* Wf3 = (const float*)d_in[25]; const float* bf3 = (const float*)d_in[26];

    const int N = in_sizes[2];
    const int E = in_sizes[1] / 2;
    const int G = out_size / 10;
    const int* src = ei;
    const int* dst = ei + E;

    const int NBK = (N + BMASK) >> BSHIFT;       // buckets (391 for N=100K)
    const int CHUNK = (E + NBLK - 1) / NBLK;

    // ---- dedicated ws regions ----
    float* B0   = (float*)d_ws;              // N*128 f32 worth (= N*256 f16)
    float* B1   = B0 + (size_t)N * 128;
    float* pool = B1 + (size_t)N * 128;      // G*32
    float* st1  = pool + (size_t)G * 32;     // 256 each
    float* st2  = st1 + 256;
    float* st3  = st2 + 256;
    int* off    = (int*)(st3 + 256);         // N+1
    int* elist  = off + (N + 1);             // E
    float* v2   = (float*)(elist + E);       // 64
    float* v3   = v2 + 64;                   // 32
    int* boff   = (int*)(v3 + 32);           // NBK+1
    int* btot   = boff + (NBK + 1);          // NBK

    // ---- CSR-phase aliases in B1 (dead before B1's activation use) ----
    int* bucketed = (int*)B1;                // E ints (12.8 MB)
    int* hist     = bucketed + E;            // NBK*NBLK ints (800 KB)

    // ---- activation aliases (stream-order safe) ----
    f16* xh    = (f16*)B0;                    // N*64  [B0 slot A]
    f16* A1    = (f16*)B1;                    // N*64  [B1 slot A] (bucketed dead)
    f16* H1    = (f16*)B0 + (size_t)N * 64;   // N*128 [B0 slot B]
    f16* Y1    = (f16*)B1 + (size_t)N * 64;   // N*128 [B1 slot B] (hist dead)
    f16* Z1    = (f16*)B0;                    // N*64  [B0 slot A] (xh dead)
    f16* H2    = (f16*)B1;                    // N*64  [B1 slot A] (A1 dead)
    f16* Y2    = (f16*)B0 + (size_t)N * 64;   // N*64  [B0 slot B] (H1 dead)
    f16* Z2    = (f16*)B0;                    // N*32  [B0 slot A] (Z1 dead)
    f16* H3    = (f16*)B1;                    // N*32  [B1 slot A] (H2 dead)
    float* Y3  = B1 + (size_t)N * 64;         // N*32 f32 [B1 slot B] (Y1 dead)

    hipMemsetAsync(pool, 0, ((size_t)G * 32 + 768) * sizeof(float), stream);

    const float invN = 1.0f / (float)N;
    const int GG = 640;

    // ---- x -> f16 ----
    conv_kernel<<<(N * 16 + 255) / 256, 256, 0, stream>>>((const float4*)x, (f16x4*)xh, N * 16);

    // ---- CSR build (bucketed, LDS atomics only) ----
    bkt_count  <<<NBLK, 256, 0, stream>>>(dst, hist, NBK, CHUNK, E);
    bkt_bscan  <<<NBK, 512, 0, stream>>>(hist, btot);
    bkt_boff   <<<1, 512, 0, stream>>>(btot, boff, off, NBK, N, E);
    bkt_scatter<<<NBLK, 256, 0, stream>>>(src, dst, hist, boff, bucketed, NBK, CHUNK, E);
    bkt_csr    <<<NBK, 512, 0, stream>>>(bucketed, boff, off, elist, N);

    // ---- Layer 1: gather(x,64) -> gemm 64->128 relu -> gemm 128->128 relu+stats
    gather_v<64, false><<<(N + 31) / 32, 256, 0, stream>>>(off, elist, xh, A1, nullptr, nullptr, N);
    gemm_mfma<64, 128, false, true, true, false, f16><<<GG, 256, 0, stream>>>(A1, W1a, b1a, H1, nullptr, nullptr, nullptr, invN, N);
    gemm_mfma<128, 128, true, true, true, false, f16><<<GG, 256, 0, stream>>>(H1, W1b, b1b, Y1, st1, nullptr, nullptr, invN, N);

    // ---- Layer 2 (commuted): Z1 = Y1 @ diag(sc1) W2a; gather+affine+relu -> H2
    prep_kernel<<<1, 64, 0, stream>>>(W2a, st1, g1, be1, v2, 128, 64, invN);
    gemm_mfma<128, 64, false, false, false, true, f16><<<GG, 256, 0, stream>>>(Y1, W2a, nullptr, Z1, nullptr, st1, g1, invN, N);
    gather_v<64, true><<<(N + 31) / 32, 256, 0, stream>>>(off, elist, Z1, H2, v2, b2a, N);
    gemm_mfma<64, 64, true, true, true, false, f16><<<GG, 256, 0, stream>>>(H2, W2b, b2b, Y2, st2, nullptr, nullptr, invN, N);

    // ---- Layer 3 (commuted): Z2 = Y2 @ diag(sc2) W3a; gather+affine+relu -> H3
    prep_kernel<<<1, 64, 0, stream>>>(W3a, st2, g2, be2, v3, 64, 32, invN);
    gemm_mfma<64, 32, false, false, false, true, f16><<<GG, 256, 0, stream>>>(Y2, W3a, nullptr, Z2, nullptr, st2, g2, invN, N);
    gather_v<32, true><<<(N + 63) / 64, 256, 0, stream>>>(off, elist, Z2, H3, v3, b3a, N);
    gemm_mfma<32, 32, true, true, true, false, float><<<GG, 256, 0, stream>>>(H3, W3b, b3b, Y3, st3, nullptr, nullptr, invN, N);

    // ---- BN3 + segmented pool ----
    bn_pool_kernel<<<(N + 511) / 512, 256, 0, stream>>>(Y3, st3, g3, be3, batch, pool, N, invN);

    // ---- pooled MLP head ----
    fc_kernel<<<G, 128, 0, stream>>>(pool, Wf1, bf1, Wf2, bf2, Wf3, bf3, (float*)d_out);
}

// Round 10
// 550.837 us; speedup vs baseline: 1.2864x; 1.0056x over previous
//
#include <hip/hip_runtime.h>

#define BN_EPS 1e-5f

typedef _Float16 f16;
typedef _Float16 f16x8 __attribute__((ext_vector_type(8)));
typedef _Float16 f16x4 __attribute__((ext_vector_type(4)));
typedef float f32x4 __attribute__((ext_vector_type(4)));

#define NBLK 512      // blocks in bucket count/scatter passes
#define BSHIFT 8      // bucket = dst >> 8  (256 nodes/bucket)
#define BMASK 255

// ================= x -> f16 convert =================
__global__ __launch_bounds__(256) void conv_kernel(const float4* __restrict__ in,
        f16x4* __restrict__ out, int n4) {
    int i = blockIdx.x * 256 + threadIdx.x;
    if (i < n4) {
        float4 v = in[i];
        f16x4 o;
        o.x = (f16)v.x; o.y = (f16)v.y; o.z = (f16)v.z; o.w = (f16)v.w;
        out[i] = o;
    }
}

// ============ CSR build, bucketed: NO per-edge global atomics ============
__global__ __launch_bounds__(256) void bkt_count(const int* __restrict__ dst,
        int* __restrict__ hist, int NBK, int CHUNK, int E) {
    __shared__ int lh[512];
    const int blk = blockIdx.x, t = threadIdx.x;
    for (int r = t; r < 512; r += 256) lh[r] = 0;
    __syncthreads();
    const int e0 = blk * CHUNK, e1 = min(E, e0 + CHUNK);
    for (int e = e0 + t; e < e1; e += 256) atomicAdd(&lh[dst[e] >> BSHIFT], 1);
    __syncthreads();
    for (int r = t; r < NBK; r += 256) hist[r * NBLK + blk] = lh[r];
}

__global__ __launch_bounds__(512) void bkt_bscan(int* __restrict__ hist,
        int* __restrict__ btot) {
    __shared__ int sh[512];
    const int b = blockIdx.x, t = threadIdx.x;
    int v = hist[b * NBLK + t];
    sh[t] = v;
    __syncthreads();
    for (int d = 1; d < 512; d <<= 1) {
        int u = (t >= d) ? sh[t - d] : 0;
        __syncthreads();
        sh[t] += u;
        __syncthreads();
    }
    hist[b * NBLK + t] = sh[t] - v;        // exclusive
    if (t == 511) btot[b] = sh[511];
}

__global__ __launch_bounds__(512) void bkt_boff(const int* __restrict__ btot,
        int* __restrict__ boff, int* __restrict__ off, int NBK, int N, int E) {
    __shared__ int sh[512];
    const int t = threadIdx.x;
    int v = (t < NBK) ? btot[t] : 0;
    sh[t] = v;
    __syncthreads();
    for (int d = 1; d < 512; d <<= 1) {
        int u = (t >= d) ? sh[t - d] : 0;
        __syncthreads();
        sh[t] += u;
        __syncthreads();
    }
    if (t < NBK) boff[t] = sh[t] - v;      // exclusive
    if (t == 0) { boff[NBK] = E; off[N] = E; }
}

__global__ __launch_bounds__(256) void bkt_scatter(const int* __restrict__ src,
        const int* __restrict__ dst, const int* __restrict__ hist,
        const int* __restrict__ boff, int* __restrict__ bucketed,
        int NBK, int CHUNK, int E) {
    __shared__ int lc[512];
    const int blk = blockIdx.x, t = threadIdx.x;
    for (int r = t; r < NBK; r += 256) lc[r] = boff[r] + hist[r * NBLK + blk];
    __syncthreads();
    const int e0 = blk * CHUNK, e1 = min(E, e0 + CHUNK);
    for (int e = e0 + t; e < e1; e += 256) {
        int d = dst[e];
        int slot = atomicAdd(&lc[d >> BSHIFT], 1);
        bucketed[slot] = ((d & BMASK) << 18) | src[e];
    }
}

__global__ __launch_bounds__(512) void bkt_csr(const int* __restrict__ bucketed,
        const int* __restrict__ boff, int* __restrict__ off,
        int* __restrict__ elist, int N) {
    __shared__ int lh[256];
    __shared__ int lc[256];
    __shared__ int sh[256];
    const int b = blockIdx.x, t = threadIdx.x;
    const int b0 = b << BSHIFT;
    const int R = min(N - b0, 256);
    const int base = boff[b], cnt = boff[b + 1] - base;
    if (t < 256) lh[t] = 0;
    __syncthreads();
    for (int i = t; i < cnt; i += 512) atomicAdd(&lh[bucketed[base + i] >> 18], 1);
    __syncthreads();
    int v = 0;
    if (t < 256) { v = lh[t]; sh[t] = v; }
    __syncthreads();
    for (int d = 1; d < 256; d <<= 1) {
        int u = 0;
        if (t < 256 && t >= d) u = sh[t - d];
        __syncthreads();
        if (t < 256) sh[t] += u;
        __syncthreads();
    }
    if (t < 256) { int ex = sh[t] - v; lh[t] = ex; lc[t] = ex; }
    __syncthreads();
    if (t < R) off[b0 + t] = base + lh[t];
    for (int i = t; i < cnt; i += 512) {
        int p = bucketed[base + i];
        int rk = atomicAdd(&lc[p >> 18], 1);
        elist[base + rk] = p & 0x3FFFF;
    }
}

// ================= vectorized gather (f16x8, 8-deep unroll) ===================
// AFFINE==false: out[i] = in[i] + sum_{s in nbrs} in[s]
// AFFINE==true : out[i] = relu( acc + cnt*v + b ),  cnt = deg+1
template<int F, bool AFFINE>
__global__ __launch_bounds__(256) void gather_v(const int* __restrict__ off,
        const int* __restrict__ elist, const f16* __restrict__ in,
        f16* __restrict__ out, const float* __restrict__ v,
        const float* __restrict__ bias, int N) {
    constexpr int TPN = F / 8;           // threads per node
    constexpr int NPB = 256 / TPN;       // nodes per block
    const int i = blockIdx.x * NPB + threadIdx.x / TPN;
    const int l = threadIdx.x & (TPN - 1);
    if (i >= N) return;
    const int j0 = l * 8;
    f16x8 s = ((const f16x8*)(in + (size_t)i * F))[l];
    float a[8];
#pragma unroll
    for (int u = 0; u < 8; u++) a[u] = (float)s[u];
    int k = off[i], e = off[i + 1];
    const float cnt = (float)(e - k + 1);
    for (; k + 8 <= e; k += 8) {
        f16x8 p0 = ((const f16x8*)(in + (size_t)elist[k + 0] * F))[l];
        f16x8 p1 = ((const f16x8*)(in + (size_t)elist[k + 1] * F))[l];
        f16x8 p2 = ((const f16x8*)(in + (size_t)elist[k + 2] * F))[l];
        f16x8 p3 = ((const f16x8*)(in + (size_t)elist[k + 3] * F))[l];
        f16x8 p4 = ((const f16x8*)(in + (size_t)elist[k + 4] * F))[l];
        f16x8 p5 = ((const f16x8*)(in + (size_t)elist[k + 5] * F))[l];
        f16x8 p6 = ((const f16x8*)(in + (size_t)elist[k + 6] * F))[l];
        f16x8 p7 = ((const f16x8*)(in + (size_t)elist[k + 7] * F))[l];
#pragma unroll
        for (int u = 0; u < 8; u++)
            a[u] += (((float)p0[u] + (float)p1[u]) + ((float)p2[u] + (float)p3[u]))
                  + (((float)p4[u] + (float)p5[u]) + ((float)p6[u] + (float)p7[u]));
    }
    for (; k + 4 <= e; k += 4) {
        f16x8 p0 = ((const f16x8*)(in + (size_t)elist[k + 0] * F))[l];
        f16x8 p1 = ((const f16x8*)(in + (size_t)elist[k + 1] * F))[l];
        f16x8 p2 = ((const f16x8*)(in + (size_t)elist[k + 2] * F))[l];
        f16x8 p3 = ((const f16x8*)(in + (size_t)elist[k + 3] * F))[l];
#pragma unroll
        for (int u = 0; u < 8; u++)
            a[u] += ((float)p0[u] + (float)p1[u]) + ((float)p2[u] + (float)p3[u]);
    }
    for (; k < e; k++) {
        f16x8 p = ((const f16x8*)(in + (size_t)elist[k] * F))[l];
#pragma unroll
        for (int u = 0; u < 8; u++) a[u] += (float)p[u];
    }
    if (AFFINE) {
        float4 vv0 = *(const float4*)(v + j0);
        float4 vv1 = *(const float4*)(v + j0 + 4);
        float4 bb0 = *(const float4*)(bias + j0);
        float4 bb1 = *(const float4*)(bias + j0 + 4);
        a[0] = fmaxf(fmaf(cnt, vv0.x, a[0] + bb0.x), 0.0f);
        a[1] = fmaxf(fmaf(cnt, vv0.y, a[1] + bb0.y), 0.0f);
        a[2] = fmaxf(fmaf(cnt, vv0.z, a[2] + bb0.z), 0.0f);
        a[3] = fmaxf(fmaf(cnt, vv0.w, a[3] + bb0.w), 0.0f);
        a[4] = fmaxf(fmaf(cnt, vv1.x, a[4] + bb1.x), 0.0f);
        a[5] = fmaxf(fmaf(cnt, vv1.y, a[5] + bb1.y), 0.0f);
        a[6] = fmaxf(fmaf(cnt, vv1.z, a[6] + bb1.z), 0.0f);
        a[7] = fmaxf(fmaf(cnt, vv1.w, a[7] + bb1.w), 0.0f);
    }
    f16x8 o;
#pragma unroll
    for (int u = 0; u < 8; u++) o[u] = (f16)a[u];
    ((f16x8*)(out + (size_t)i * F))[l] = o;
}

// ================= prep: v[j] = sum_k sh[k] * W[k][j] =========================
__global__ __launch_bounds__(64) void prep_kernel(const float* __restrict__ W,
        const float* __restrict__ stats, const float* __restrict__ g,
        const float* __restrict__ be, float* __restrict__ v,
        int FIN, int FOUT, float invN) {
    int j = threadIdx.x;
    if (j >= FOUT) return;
    float acc = 0.0f;
    for (int k = 0; k < FIN; k++) {
        float mu = stats[k] * invN;
        float var = fmaxf(stats[FIN + k] * invN - mu * mu, 0.0f);
        float sc = rsqrtf(var + BN_EPS) * g[k];
        float sh = be[k] - mu * sc;
        acc = fmaf(sh, W[(size_t)k * FOUT + j], acc);
    }
    v[j] = acc;
}

// ======= wfrag: W [FIN,FOUT] f32 -> MFMA-frag-ordered f16 (optional BN scale) =
// frag element f = ((s*NT + t)<<9) + lane*8 + j  <->  W[k][n],
//   k = s*32 + (lane>>4)*8 + j,  n = t*16 + (lane&15)
__global__ __launch_bounds__(256) void wfrag_kernel(const float* __restrict__ W,
        f16* __restrict__ out, int FIN, int FOUT,
        const float* __restrict__ stats, const float* __restrict__ g, float invN) {
    int f = blockIdx.x * 256 + threadIdx.x;
    if (f >= FIN * FOUT) return;
    int j = f & 7;
    int lane = (f >> 3) & 63;
    int tile = f >> 9;
    int NT = FOUT >> 4;
    int t = tile % NT, s = tile / NT;
    int k = s * 32 + (lane >> 4) * 8 + j;
    int n = t * 16 + (lane & 15);
    float w = W[(size_t)k * FOUT + n];
    if (stats) {
        float mu = stats[k] * invN;
        float var = fmaxf(stats[FIN + k] * invN - mu * mu, 0.0f);
        w *= rsqrtf(var + BN_EPS) * g[k];
    }
    out[f] = (f16)w;
}

// ================= MFMA GEMM (pre-fragged W, no LDS staging) ==================
// Out = [relu]( A @ Wf + (bias?) ), optional col stats. N % 16 == 0.
template<int FIN, int FOUT, bool STATS, bool RELU, bool BIAS, typename OutT>
__global__ __launch_bounds__(256) void gemm_mfma(const f16* __restrict__ A,
        const f16* __restrict__ Wf, const float* __restrict__ bias,
        OutT* __restrict__ Out, float* __restrict__ stats, int N) {
    constexpr int NS = FIN / 32;    // k-steps
    constexpr int NT = FOUT / 16;   // n-tiles
    __shared__ float Ss[STATS ? 2 * FOUT : 1];
    if (STATS) {
        for (int i = threadIdx.x; i < 2 * FOUT; i += 256) Ss[i] = 0.0f;
        __syncthreads();
    }
    const int wid = threadIdx.x >> 6;
    const int lane = threadIdx.x & 63;
    const int col = lane & 15;
    const int quad = lane >> 4;

    f16x8 Bf[NS][NT];
#pragma unroll
    for (int s = 0; s < NS; s++)
#pragma unroll
        for (int t = 0; t < NT; t++)
            Bf[s][t] = *(const f16x8*)&Wf[((s * NT + t) << 9) + (lane << 3)];

    float bj[NT];
#pragma unroll
    for (int t = 0; t < NT; t++) bj[t] = BIAS ? bias[t * 16 + col] : 0.0f;

    float ls[NT], ls2[NT];
#pragma unroll
    for (int t = 0; t < NT; t++) { ls[t] = 0.0f; ls2[t] = 0.0f; }

    const int S = N >> 4;
    for (int sidx = blockIdx.x * 4 + wid; sidx < S; sidx += (int)gridDim.x * 4) {
        const int m0 = sidx << 4;
        const f16* a0 = A + (size_t)(m0 + col) * FIN + (quad << 3);
        f16x8 Af[NS];
#pragma unroll
        for (int s = 0; s < NS; s++) Af[s] = *(const f16x8*)(a0 + s * 32);
        f32x4 acc[NT];
#pragma unroll
        for (int t = 0; t < NT; t++) acc[t] = (f32x4){bj[t], bj[t], bj[t], bj[t]};
#pragma unroll
        for (int t = 0; t < NT; t++)
#pragma unroll
            for (int s = 0; s < NS; s++)
                acc[t] = __builtin_amdgcn_mfma_f32_16x16x32_f16(Af[s], Bf[s][t], acc[t], 0, 0, 0);
#pragma unroll
        for (int t = 0; t < NT; t++) {
            float v0 = acc[t][0], v1 = acc[t][1], v2 = acc[t][2], v3 = acc[t][3];
            if (RELU) {
                v0 = fmaxf(v0, 0.0f); v1 = fmaxf(v1, 0.0f);
                v2 = fmaxf(v2, 0.0f); v3 = fmaxf(v3, 0.0f);
            }
            if (STATS) {
                ls[t]  += (v0 + v1) + (v2 + v3);
                ls2[t] += (v0 * v0 + v1 * v1) + (v2 * v2 + v3 * v3);
            }
            OutT* o = Out + (size_t)(m0 + quad * 4) * FOUT + t * 16 + col;
            o[0]        = (OutT)v0;
            o[FOUT]     = (OutT)v1;
            o[2 * FOUT] = (OutT)v2;
            o[3 * FOUT] = (OutT)v3;
        }
    }

    if (STATS) {
#pragma unroll
        for (int t = 0; t < NT; t++) {
            float s1 = ls[t], s2 = ls2[t];
            s1 += __shfl_xor(s1, 16); s1 += __shfl_xor(s1, 32);
            s2 += __shfl_xor(s2, 16); s2 += __shfl_xor(s2, 32);
            if (quad == 0) {
                atomicAdd(&Ss[t * 16 + col], s1);
                atomicAdd(&Ss[FOUT + t * 16 + col], s2);
            }
        }
        __syncthreads();
        for (int i = threadIdx.x; i < 2 * FOUT; i += 256) atomicAdd(&stats[i], Ss[i]);
    }
}

// ================= layer-3 BN + segmented pool (batch sorted) =================
__global__ __launch_bounds__(256) void bn_pool_kernel(const float* __restrict__ y,
        const float* __restrict__ stats, const float* __restrict__ gw,
        const float* __restrict__ bw, const int* __restrict__ batch,
        float* __restrict__ pool, int N, float invN) {
    constexpr int F = 32, CH = 64;
    int q = threadIdx.x >> 5;
    int j = threadIdx.x & 31;
    int r0 = (blockIdx.x * 8 + q) * CH;
    if (r0 >= N) return;
    int r1 = min(r0 + CH, N);
    float mu = stats[j] * invN;
    float var = fmaxf(stats[F + j] * invN - mu * mu, 0.0f);
    float sc = rsqrtf(var + BN_EPS) * gw[j];
    float sh = bw[j] - mu * sc;
    int curg = batch[r0];
    float acc = 0.0f;
    for (int r = r0; r < r1; r++) {
        int g = batch[r];
        if (g != curg) {
            atomicAdd(pool + (size_t)curg * 32 + j, acc);
            acc = 0.0f;
            curg = g;
        }
        acc = fmaf(y[(size_t)r * 32 + j], sc, sh + acc);
    }
    atomicAdd(pool + (size_t)curg * 32 + j, acc);
}

// ================= FC head =================
__global__ __launch_bounds__(128) void fc_kernel(const float* __restrict__ pool,
        const float* __restrict__ Wf1, const float* __restrict__ bf1,
        const float* __restrict__ Wf2, const float* __restrict__ bf2,
        const float* __restrict__ Wf3, const float* __restrict__ bf3,
        float* __restrict__ out) {
    __shared__ float zin[32];
    __shared__ float h1[128];
    __shared__ float h2[64];
    const int gidx = blockIdx.x;
    const int t = threadIdx.x;
    if (t < 32) zin[t] = pool[(size_t)gidx * 32 + t];
    __syncthreads();
    {
        float a = bf1[t];
        for (int k = 0; k < 32; k++) a = fmaf(zin[k], Wf1[k * 128 + t], a);
        h1[t] = fmaxf(a, 0.0f);
    }
    __syncthreads();
    if (t < 64) {
        float a = bf2[t];
        for (int k = 0; k < 128; k++) a = fmaf(h1[k], Wf2[k * 64 + t], a);
        h2[t] = fmaxf(a, 0.0f);
    }
    __syncthreads();
    if (t < 10) {
        float a = bf3[t];
        for (int k = 0; k < 64; k++) a = fmaf(h2[k], Wf3[k * 10 + t], a);
        out[(size_t)gidx * 10 + t] = a;
    }
}

extern "C" void kernel_launch(void* const* d_in, const int* in_sizes, int n_in,
                              void* d_out, int out_size, void* d_ws, size_t ws_size,
                              hipStream_t stream) {
    const float* x   = (const float*)d_in[0];
    const int*  ei   = (const int*)d_in[1];
    const int*  batch= (const int*)d_in[2];
    const float* W1a = (const float*)d_in[3];  const float* b1a = (const float*)d_in[4];
    const float* W1b = (const float*)d_in[5];  const float* b1b = (const float*)d_in[6];
    const float* g1  = (const float*)d_in[7];  const float* be1 = (const float*)d_in[8];
    const float* W2a = (const float*)d_in[9];  const float* b2a = (const float*)d_in[10];
    const float* W2b = (const float*)d_in[11]; const float* b2b = (const float*)d_in[12];
    const float* g2  = (const float*)d_in[13]; const float* be2 = (const float*)d_in[14];
    const float* W3a = (const float*)d_in[15]; const float* b3a = (const float*)d_in[16];
    const float* W3b = (const float*)d_in[17]; const float* b3b = (const float*)d_in[18];
    const float* g3  = (const float*)d_in[19]; const float* be3 = (const float*)d_in[20];
    const float* Wf1 = (const float*)d_in[21]; const float* bf1 = (const float*)d_in[22];
    const float* Wf2 = (const float*)d_in[23]; const float* bf2 = (const float*)d_in[24];
    const float* Wf3 = (const float*)d_in[25]; const float* bf3 = (const float*)d_in[26];

    const int N = in_sizes[2];
    const int E = in_sizes[1] / 2;
    const int G = out_size / 10;
    const int* src = ei;
    const int* dst = ei + E;

    const int NBK = (N + BMASK) >> BSHIFT;       // buckets (391 for N=100K)
    const int CHUNK = (E + NBLK - 1) / NBLK;

    // ---- dedicated ws regions ----
    float* B0   = (float*)d_ws;              // N*128 f32 worth (= N*256 f16)
    float* B1   = B0 + (size_t)N * 128;
    float* pool = B1 + (size_t)N * 128;      // G*32
    float* st1  = pool + (size_t)G * 32;     // 256 each
    float* st2  = st1 + 256;
    float* st3  = st2 + 256;
    int* off    = (int*)(st3 + 256);         // N+1
    int* elist  = off + (N + 1);             // E
    float* v2   = (float*)(elist + E);       // 64
    float* v3   = v2 + 64;                   // 32
    int* boff   = (int*)(v3 + 32);           // NBK+1
    int* btot   = boff + (NBK + 1);          // NBK
    f16* Wh1a   = (f16*)(btot + NBK);        // 8K
    f16* Wh1b   = Wh1a + 64 * 128;           // 16K
    f16* Wh2a   = Wh1b + 128 * 128;          // 8K
    f16* Wh2b   = Wh2a + 128 * 64;           // 4K
    f16* Wh3a   = Wh2b + 64 * 64;            // 2K
    f16* Wh3b   = Wh3a + 64 * 32;            // 1K

    // ---- CSR-phase aliases in B1 (dead before B1's activation use) ----
    int* bucketed = (int*)B1;                // E ints (12.8 MB)
    int* hist     = bucketed + E;            // NBK*NBLK ints (800 KB)

    // ---- activation aliases (stream-order safe) ----
    f16* xh    = (f16*)B0;                    // N*64  [B0 slot A]
    f16* A1    = (f16*)B1;                    // N*64  [B1 slot A] (bucketed dead)
    f16* H1    = (f16*)B0 + (size_t)N * 64;   // N*128 [B0 slot B]
    f16* Y1    = (f16*)B1 + (size_t)N * 64;   // N*128 [B1 slot B] (hist dead)
    f16* Z1    = (f16*)B0;                    // N*64  [B0 slot A] (xh dead)
    f16* H2    = (f16*)B1;                    // N*64  [B1 slot A] (A1 dead)
    f16* Y2    = (f16*)B0 + (size_t)N * 64;   // N*64  [B0 slot B] (H1 dead)
    f16* Z2    = (f16*)B0;                    // N*32  [B0 slot A] (Z1 dead)
    f16* H3    = (f16*)B1;                    // N*32  [B1 slot A] (H2 dead)
    float* Y3  = B1 + (size_t)N * 64;         // N*32 f32 [B1 slot B] (Y1 dead)

    hipMemsetAsync(pool, 0, ((size_t)G * 32 + 768) * sizeof(float), stream);

    const float invN = 1.0f / (float)N;
    const int GG = 640;

    // ---- x -> f16 ----
    conv_kernel<<<(N * 16 + 255) / 256, 256, 0, stream>>>((const float4*)x, (f16x4*)xh, N * 16);

    // ---- static W pre-frag (no stats dependency) ----
    wfrag_kernel<<<32, 256, 0, stream>>>(W1a, Wh1a, 64, 128, nullptr, nullptr, invN);
    wfrag_kernel<<<64, 256, 0, stream>>>(W1b, Wh1b, 128, 128, nullptr, nullptr, invN);
    wfrag_kernel<<<16, 256, 0, stream>>>(W2b, Wh2b, 64, 64, nullptr, nullptr, invN);
    wfrag_kernel<<<4, 256, 0, stream>>>(W3b, Wh3b, 32, 32, nullptr, nullptr, invN);

    // ---- CSR build (bucketed, LDS atomics only) ----
    bkt_count  <<<NBLK, 256, 0, stream>>>(dst, hist, NBK, CHUNK, E);
    bkt_bscan  <<<NBK, 512, 0, stream>>>(hist, btot);
    bkt_boff   <<<1, 512, 0, stream>>>(btot, boff, off, NBK, N, E);
    bkt_scatter<<<NBLK, 256, 0, stream>>>(src, dst, hist, boff, bucketed, NBK, CHUNK, E);
    bkt_csr    <<<NBK, 512, 0, stream>>>(bucketed, boff, off, elist, N);

    // ---- Layer 1: gather(x,64) -> gemm 64->128 relu -> gemm 128->128 relu+stats
    gather_v<64, false><<<(N + 31) / 32, 256, 0, stream>>>(off, elist, xh, A1, nullptr, nullptr, N);
    gemm_mfma<64, 128, false, true, true, f16><<<GG, 256, 0, stream>>>(A1, Wh1a, b1a, H1, nullptr, N);
    gemm_mfma<128, 128, true, true, true, f16><<<GG, 256, 0, stream>>>(H1, Wh1b, b1b, Y1, st1, N);

    // ---- Layer 2 (commuted): Z1 = Y1 @ diag(sc1) W2a; gather+affine+relu -> H2
    prep_kernel<<<1, 64, 0, stream>>>(W2a, st1, g1, be1, v2, 128, 64, invN);
    wfrag_kernel<<<32, 256, 0, stream>>>(W2a, Wh2a, 128, 64, st1, g1, invN);
    gemm_mfma<128, 64, false, false, false, f16><<<GG, 256, 0, stream>>>(Y1, Wh2a, nullptr, Z1, nullptr, N);
    gather_v<64, true><<<(N + 31) / 32, 256, 0, stream>>>(off, elist, Z1, H2, v2, b2a, N);
    gemm_mfma<64, 64, true, true, true, f16><<<GG, 256, 0, stream>>>(H2, Wh2b, b2b, Y2, st2, N);

    // ---- Layer 3 (commuted): Z2 = Y2 @ diag(sc2) W3a; gather+affine+relu -> H3
    prep_kernel<<<1, 64, 0, stream>>>(W3a, st2, g2, be2, v3, 64, 32, invN);
    wfrag_kernel<<<8, 256, 0, stream>>>(W3a, Wh3a, 64, 32, st2, g2, invN);
    gemm_mfma<64, 32, false, false, false, f16><<<GG, 256, 0, stream>>>(Y2, Wh3a, nullptr, Z2, nullptr, N);
    gather_v<32, true><<<(N + 63) / 64, 256, 0, stream>>>(off, elist, Z2, H3, v3, b3a, N);
    gemm_mfma<32, 32, true, true, true, float><<<GG, 256, 0, stream>>>(H3, Wh3b, b3b, Y3, st3, N);

    // ---- BN3 + segmented pool ----
    bn_pool_kernel<<<(N + 511) / 512, 256, 0, stream>>>(Y3, st3, g3, be3, batch, pool, N, invN);

    // ---- pooled MLP head ----
    fc_kernel<<<G, 128, 0, stream>>>(pool, Wf1, bf1, Wf2, bf2, Wf3, bf3, (float*)d_out);
}

// Round 11
// 517.329 us; speedup vs baseline: 1.3698x; 1.0648x over previous
//
#include <hip/hip_runtime.h>

#define BN_EPS 1e-5f

typedef _Float16 f16;
typedef _Float16 f16x8 __attribute__((ext_vector_type(8)));
typedef _Float16 f16x4 __attribute__((ext_vector_type(4)));
typedef float f32x4 __attribute__((ext_vector_type(4)));

#define NBLK 512      // blocks in bucket count/scatter passes
#define BSHIFT 8      // bucket = dst >> 8  (256 nodes/bucket)
#define BMASK 255

// ======= wfrag mapping (device helper): W [FIN,FOUT] f32 -> frag f16 =========
// frag element f = ((s*NT + t)<<9) + lane*8 + j  <->  W[k][n],
//   k = s*32 + (lane>>4)*8 + j,  n = t*16 + (lane&15)
__device__ inline void wfrag_one(const float* __restrict__ W, f16* __restrict__ out,
        int FIN, int FOUT, int f,
        const float* __restrict__ stats, const float* __restrict__ g, float invN) {
    int j = f & 7;
    int lane = (f >> 3) & 63;
    int tile = f >> 9;
    int NT = FOUT >> 4;
    int t = tile % NT, s = tile / NT;
    int k = s * 32 + (lane >> 4) * 8 + j;
    int n = t * 16 + (lane & 15);
    float w = W[(size_t)k * FOUT + n];
    if (stats) {
        float mu = stats[k] * invN;
        float var = fmaxf(stats[FIN + k] * invN - mu * mu, 0.0f);
        w *= rsqrtf(var + BN_EPS) * g[k];
    }
    out[f] = (f16)w;
}

// ================= fused setup: x->f16 + 4 static W frags =====================
__global__ __launch_bounds__(256) void setup_kernel(const float4* __restrict__ x,
        f16x4* __restrict__ xh, int n4,
        const float* __restrict__ W1a, f16* __restrict__ Wh1a,
        const float* __restrict__ W1b, f16* __restrict__ Wh1b,
        const float* __restrict__ W2b, f16* __restrict__ Wh2b,
        const float* __restrict__ W3b, f16* __restrict__ Wh3b) {
    const int BC = (n4 + 255) / 256;
    int bid = blockIdx.x;
    if (bid < BC) {
        int i = bid * 256 + threadIdx.x;
        if (i < n4) {
            float4 v = x[i];
            f16x4 o;
            o.x = (f16)v.x; o.y = (f16)v.y; o.z = (f16)v.z; o.w = (f16)v.w;
            xh[i] = o;
        }
        return;
    }
    bid -= BC;
    if (bid < 32) { wfrag_one(W1a, Wh1a, 64, 128, bid * 256 + threadIdx.x, nullptr, nullptr, 0.f); return; }
    bid -= 32;
    if (bid < 64) { wfrag_one(W1b, Wh1b, 128, 128, bid * 256 + threadIdx.x, nullptr, nullptr, 0.f); return; }
    bid -= 64;
    if (bid < 16) { wfrag_one(W2b, Wh2b, 64, 64, bid * 256 + threadIdx.x, nullptr, nullptr, 0.f); return; }
    bid -= 16;
    wfrag_one(W3b, Wh3b, 32, 32, bid * 256 + threadIdx.x, nullptr, nullptr, 0.f);
}

// ===== fused layer prep: block 0 computes v[]; blocks 1.. do scaled wfrag =====
__global__ __launch_bounds__(256) void layerprep_kernel(const float* __restrict__ W,
        f16* __restrict__ Wh, int FIN, int FOUT,
        const float* __restrict__ stats, const float* __restrict__ g,
        const float* __restrict__ be, float* __restrict__ v, float invN) {
    if (blockIdx.x == 0) {
        int j = threadIdx.x;
        if (j >= FOUT) return;
        float acc = 0.0f;
        for (int k = 0; k < FIN; k++) {
            float mu = stats[k] * invN;
            float var = fmaxf(stats[FIN + k] * invN - mu * mu, 0.0f);
            float sc = rsqrtf(var + BN_EPS) * g[k];
            float sh = be[k] - mu * sc;
            acc = fmaf(sh, W[(size_t)k * FOUT + j], acc);
        }
        v[j] = acc;
        return;
    }
    int f = (blockIdx.x - 1) * 256 + threadIdx.x;
    if (f < FIN * FOUT) wfrag_one(W, Wh, FIN, FOUT, f, stats, g, invN);
}

// ============ CSR build, bucketed: NO per-edge global atomics ============
__global__ __launch_bounds__(256) void bkt_count(const int* __restrict__ dst,
        int* __restrict__ hist, int NBK, int CHUNK, int E) {
    __shared__ int lh[512];
    const int blk = blockIdx.x, t = threadIdx.x;
    for (int r = t; r < 512; r += 256) lh[r] = 0;
    __syncthreads();
    const int e0 = blk * CHUNK, e1 = min(E, e0 + CHUNK);
    const int nq = (e1 - e0) >> 2;
    const int4* d4 = (const int4*)(dst + e0);
    for (int q = t; q < nq; q += 256) {
        int4 v = d4[q];
        atomicAdd(&lh[v.x >> BSHIFT], 1);
        atomicAdd(&lh[v.y >> BSHIFT], 1);
        atomicAdd(&lh[v.z >> BSHIFT], 1);
        atomicAdd(&lh[v.w >> BSHIFT], 1);
    }
    for (int e = e0 + (nq << 2) + t; e < e1; e += 256) atomicAdd(&lh[dst[e] >> BSHIFT], 1);
    __syncthreads();
    for (int r = t; r < NBK; r += 256) hist[r * NBLK + blk] = lh[r];
}

__global__ __launch_bounds__(512) void bkt_bscan(int* __restrict__ hist,
        int* __restrict__ btot) {
    __shared__ int sh[512];
    const int b = blockIdx.x, t = threadIdx.x;
    int v = hist[b * NBLK + t];
    sh[t] = v;
    __syncthreads();
    for (int d = 1; d < 512; d <<= 1) {
        int u = (t >= d) ? sh[t - d] : 0;
        __syncthreads();
        sh[t] += u;
        __syncthreads();
    }
    hist[b * NBLK + t] = sh[t] - v;        // exclusive
    if (t == 511) btot[b] = sh[511];
}

__global__ __launch_bounds__(512) void bkt_boff(const int* __restrict__ btot,
        int* __restrict__ boff, int* __restrict__ off, int NBK, int N, int E) {
    __shared__ int sh[512];
    const int t = threadIdx.x;
    int v = (t < NBK) ? btot[t] : 0;
    sh[t] = v;
    __syncthreads();
    for (int d = 1; d < 512; d <<= 1) {
        int u = (t >= d) ? sh[t - d] : 0;
        __syncthreads();
        sh[t] += u;
        __syncthreads();
    }
    if (t < NBK) boff[t] = sh[t] - v;      // exclusive
    if (t == 0) { boff[NBK] = E; off[N] = E; }
}

__global__ __launch_bounds__(256) void bkt_scatter(const int* __restrict__ src,
        const int* __restrict__ dst, const int* __restrict__ hist,
        const int* __restrict__ boff, int* __restrict__ bucketed,
        int NBK, int CHUNK, int E) {
    __shared__ int lc[512];
    const int blk = blockIdx.x, t = threadIdx.x;
    for (int r = t; r < NBK; r += 256) lc[r] = boff[r] + hist[r * NBLK + blk];
    __syncthreads();
    const int e0 = blk * CHUNK, e1 = min(E, e0 + CHUNK);
    const int nq = (e1 - e0) >> 2;
    const int4* d4 = (const int4*)(dst + e0);
    const int4* s4 = (const int4*)(src + e0);
    for (int q = t; q < nq; q += 256) {
        int4 d = d4[q];
        int4 s = s4[q];
        int sl;
        sl = atomicAdd(&lc[d.x >> BSHIFT], 1); bucketed[sl] = ((d.x & BMASK) << 18) | s.x;
        sl = atomicAdd(&lc[d.y >> BSHIFT], 1); bucketed[sl] = ((d.y & BMASK) << 18) | s.y;
        sl = atomicAdd(&lc[d.z >> BSHIFT], 1); bucketed[sl] = ((d.z & BMASK) << 18) | s.z;
        sl = atomicAdd(&lc[d.w >> BSHIFT], 1); bucketed[sl] = ((d.w & BMASK) << 18) | s.w;
    }
    for (int e = e0 + (nq << 2) + t; e < e1; e += 256) {
        int d = dst[e];
        int slot = atomicAdd(&lc[d >> BSHIFT], 1);
        bucketed[slot] = ((d & BMASK) << 18) | src[e];
    }
}

__global__ __launch_bounds__(512) void bkt_csr(const int* __restrict__ bucketed,
        const int* __restrict__ boff, int* __restrict__ off,
        int* __restrict__ elist, int N) {
    __shared__ int lh[256];
    __shared__ int lc[256];
    __shared__ int sh[256];
    const int b = blockIdx.x, t = threadIdx.x;
    const int b0 = b << BSHIFT;
    const int R = min(N - b0, 256);
    const int base = boff[b], cnt = boff[b + 1] - base;
    if (t < 256) lh[t] = 0;
    __syncthreads();
    for (int i = t; i < cnt; i += 512) atomicAdd(&lh[bucketed[base + i] >> 18], 1);
    __syncthreads();
    int v = 0;
    if (t < 256) { v = lh[t]; sh[t] = v; }
    __syncthreads();
    for (int d = 1; d < 256; d <<= 1) {
        int u = 0;
        if (t < 256 && t >= d) u = sh[t - d];
        __syncthreads();
        if (t < 256) sh[t] += u;
        __syncthreads();
    }
    if (t < 256) { int ex = sh[t] - v; lh[t] = ex; lc[t] = ex; }
    __syncthreads();
    if (t < R) off[b0 + t] = base + lh[t];
    for (int i = t; i < cnt; i += 512) {
        int p = bucketed[base + i];
        int rk = atomicAdd(&lc[p >> 18], 1);
        elist[base + rk] = p & 0x3FFFF;
    }
}

// ======== gather: f16x8 lanes, group-4 software pipeline (prefetch) ===========
// AFFINE==false: out[i] = in[i] + sum_{s in nbrs} in[s]
// AFFINE==true : out[i] = relu( acc + cnt*v + b ),  cnt = deg+1
template<int F, bool AFFINE>
__global__ __launch_bounds__(256) void gather_v(const int* __restrict__ off,
        const int* __restrict__ elist, const f16* __restrict__ in,
        f16* __restrict__ out, const float* __restrict__ v,
        const float* __restrict__ bias, int N) {
    constexpr int TPN = F / 8;           // threads per node
    constexpr int NPB = 256 / TPN;       // nodes per block
    const int i = blockIdx.x * NPB + threadIdx.x / TPN;
    const int l = threadIdx.x & (TPN - 1);
    if (i >= N) return;
    const int j0 = l * 8;
    const f16x8* __restrict__ inv = (const f16x8*)in;
    f16x8 s = inv[(size_t)i * TPN + l];
    float a[8];
#pragma unroll
    for (int u = 0; u < 8; u++) a[u] = (float)s[u];
    int k = off[i], e = off[i + 1];
    const float cnt = (float)(e - k + 1);
    f16x8 c0, c1, c2, c3;
    if (k + 4 <= e) {
        c0 = inv[(size_t)elist[k + 0] * TPN + l];
        c1 = inv[(size_t)elist[k + 1] * TPN + l];
        c2 = inv[(size_t)elist[k + 2] * TPN + l];
        c3 = inv[(size_t)elist[k + 3] * TPN + l];
        k += 4;
        for (; k + 4 <= e; k += 4) {
            f16x8 d0 = inv[(size_t)elist[k + 0] * TPN + l];
            f16x8 d1 = inv[(size_t)elist[k + 1] * TPN + l];
            f16x8 d2 = inv[(size_t)elist[k + 2] * TPN + l];
            f16x8 d3 = inv[(size_t)elist[k + 3] * TPN + l];
#pragma unroll
            for (int u = 0; u < 8; u++)
                a[u] += ((float)c0[u] + (float)c1[u]) + ((float)c2[u] + (float)c3[u]);
            c0 = d0; c1 = d1; c2 = d2; c3 = d3;
        }
#pragma unroll
        for (int u = 0; u < 8; u++)
            a[u] += ((float)c0[u] + (float)c1[u]) + ((float)c2[u] + (float)c3[u]);
    }
    for (; k < e; k++) {
        f16x8 p = inv[(size_t)elist[k] * TPN + l];
#pragma unroll
        for (int u = 0; u < 8; u++) a[u] += (float)p[u];
    }
    if (AFFINE) {
        float4 vv0 = *(const float4*)(v + j0);
        float4 vv1 = *(const float4*)(v + j0 + 4);
        float4 bb0 = *(const float4*)(bias + j0);
        float4 bb1 = *(const float4*)(bias + j0 + 4);
        a[0] = fmaxf(fmaf(cnt, vv0.x, a[0] + bb0.x), 0.0f);
        a[1] = fmaxf(fmaf(cnt, vv0.y, a[1] + bb0.y), 0.0f);
        a[2] = fmaxf(fmaf(cnt, vv0.z, a[2] + bb0.z), 0.0f);
        a[3] = fmaxf(fmaf(cnt, vv0.w, a[3] + bb0.w), 0.0f);
        a[4] = fmaxf(fmaf(cnt, vv1.x, a[4] + bb1.x), 0.0f);
        a[5] = fmaxf(fmaf(cnt, vv1.y, a[5] + bb1.y), 0.0f);
        a[6] = fmaxf(fmaf(cnt, vv1.z, a[6] + bb1.z), 0.0f);
        a[7] = fmaxf(fmaf(cnt, vv1.w, a[7] + bb1.w), 0.0f);
    }
    f16x8 o;
#pragma unroll
    for (int u = 0; u < 8; u++) o[u] = (f16)a[u];
    ((f16x8*)(out))[(size_t)i * TPN + l] = o;
}

// ======= MFMA GEMM (pre-fragged W, column-tiled to cap VGPR pressure) =========
// Out = [relu]( A @ Wf + (bias?) ), optional col stats. N % 16 == 0.
// CT = columns handled per block (<= FOUT); NCB = FOUT/CT column-blocks.
template<int FIN, int FOUT, int CT, bool STATS, bool RELU, bool BIAS, typename OutT>
__global__ __launch_bounds__(256) void gemm_mfma(const f16* __restrict__ A,
        const f16* __restrict__ Wf, const float* __restrict__ bias,
        OutT* __restrict__ Out, float* __restrict__ stats, int N) {
    constexpr int NS = FIN / 32;     // k-steps
    constexpr int NTF = FOUT / 16;   // total n-tiles in Wf
    constexpr int NT = CT / 16;      // n-tiles this block
    constexpr int NCB = FOUT / CT;
    __shared__ float Ss[STATS ? 2 * CT : 1];
    if (STATS) {
        for (int i = threadIdx.x; i < 2 * CT; i += 256) Ss[i] = 0.0f;
        __syncthreads();
    }
    const int cb = blockIdx.x % NCB;
    const int rb = blockIdx.x / NCB;
    const int RB = gridDim.x / NCB;
    const int t0 = cb * NT;
    const int wid = threadIdx.x >> 6;
    const int lane = threadIdx.x & 63;
    const int col = lane & 15;
    const int quad = lane >> 4;

    f16x8 Bf[NS][NT];
#pragma unroll
    for (int s = 0; s < NS; s++)
#pragma unroll
        for (int t = 0; t < NT; t++)
            Bf[s][t] = *(const f16x8*)&Wf[((s * NTF + t0 + t) << 9) + (lane << 3)];

    float bj[NT];
#pragma unroll
    for (int t = 0; t < NT; t++) bj[t] = BIAS ? bias[(t0 + t) * 16 + col] : 0.0f;

    float ls[NT], ls2[NT];
#pragma unroll
    for (int t = 0; t < NT; t++) { ls[t] = 0.0f; ls2[t] = 0.0f; }

    const int S = N >> 4;
    for (int sidx = rb * 4 + wid; sidx < S; sidx += RB * 4) {
        const int m0 = sidx << 4;
        const f16* a0 = A + (size_t)(m0 + col) * FIN + (quad << 3);
        f16x8 Af[NS];
#pragma unroll
        for (int s = 0; s < NS; s++) Af[s] = *(const f16x8*)(a0 + s * 32);
        f32x4 acc[NT];
#pragma unroll
        for (int t = 0; t < NT; t++) acc[t] = (f32x4){bj[t], bj[t], bj[t], bj[t]};
#pragma unroll
        for (int t = 0; t < NT; t++)
#pragma unroll
            for (int s = 0; s < NS; s++)
                acc[t] = __builtin_amdgcn_mfma_f32_16x16x32_f16(Af[s], Bf[s][t], acc[t], 0, 0, 0);
#pragma unroll
        for (int t = 0; t < NT; t++) {
            float v0 = acc[t][0], v1 = acc[t][1], v2 = acc[t][2], v3 = acc[t][3];
            if (RELU) {
                v0 = fmaxf(v0, 0.0f); v1 = fmaxf(v1, 0.0f);
                v2 = fmaxf(v2, 0.0f); v3 = fmaxf(v3, 0.0f);
            }
            if (STATS) {
                ls[t]  += (v0 + v1) + (v2 + v3);
                ls2[t] += (v0 * v0 + v1 * v1) + (v2 * v2 + v3 * v3);
            }
            OutT* o = Out + (size_t)(m0 + quad * 4) * FOUT + (t0 + t) * 16 + col;
            o[0]        = (OutT)v0;
            o[FOUT]     = (OutT)v1;
            o[2 * FOUT] = (OutT)v2;
            o[3 * FOUT] = (OutT)v3;
        }
    }

    if (STATS) {
#pragma unroll
        for (int t = 0; t < NT; t++) {
            float s1 = ls[t], s2 = ls2[t];
            s1 += __shfl_xor(s1, 16); s1 += __shfl_xor(s1, 32);
            s2 += __shfl_xor(s2, 16); s2 += __shfl_xor(s2, 32);
            if (quad == 0) {
                atomicAdd(&Ss[t * 16 + col], s1);
                atomicAdd(&Ss[CT + t * 16 + col], s2);
            }
        }
        __syncthreads();
        for (int i = threadIdx.x; i < CT; i += 256) {
            atomicAdd(&stats[cb * CT + i], Ss[i]);
            atomicAdd(&stats[FOUT + cb * CT + i], Ss[CT + i]);
        }
    }
}

// ================= layer-3 BN + segmented pool (batch sorted) =================
__global__ __launch_bounds__(256) void bn_pool_kernel(const float* __restrict__ y,
        const float* __restrict__ stats, const float* __restrict__ gw,
        const float* __restrict__ bw, const int* __restrict__ batch,
        float* __restrict__ pool, int N, float invN) {
    constexpr int F = 32, CH = 64;
    int q = threadIdx.x >> 5;
    int j = threadIdx.x & 31;
    int r0 = (blockIdx.x * 8 + q) * CH;
    if (r0 >= N) return;
    int r1 = min(r0 + CH, N);
    float mu = stats[j] * invN;
    float var = fmaxf(stats[F + j] * invN - mu * mu, 0.0f);
    float sc = rsqrtf(var + BN_EPS) * gw[j];
    float sh = bw[j] - mu * sc;
    int curg = batch[r0];
    float acc = 0.0f;
    for (int r = r0; r < r1; r++) {
        int g = batch[r];
        if (g != curg) {
            atomicAdd(pool + (size_t)curg * 32 + j, acc);
            acc = 0.0f;
            curg = g;
        }
        acc = fmaf(y[(size_t)r * 32 + j], sc, sh + acc);
    }
    atomicAdd(pool + (size_t)curg * 32 + j, acc);
}

// ================= FC head =================
__global__ __launch_bounds__(128) void fc_kernel(const float* __restrict__ pool,
        const float* __restrict__ Wf1, const float* __restrict__ bf1,
        const float* __restrict__ Wf2, const float* __restrict__ bf2,
        const float* __restrict__ Wf3, const float* __restrict__ bf3,
        float* __restrict__ out) {
    __shared__ float zin[32];
    __shared__ float h1[128];
    __shared__ float h2[64];
    const int gidx = blockIdx.x;
    const int t = threadIdx.x;
    if (t < 32) zin[t] = pool[(size_t)gidx * 32 + t];
    __syncthreads();
    {
        float a = bf1[t];
        for (int k = 0; k < 32; k++) a = fmaf(zin[k], Wf1[k * 128 + t], a);
        h1[t] = fmaxf(a, 0.0f);
    }
    __syncthreads();
    if (t < 64) {
        float a = bf2[t];
        for (int k = 0; k < 128; k++) a = fmaf(h1[k], Wf2[k * 64 + t], a);
        h2[t] = fmaxf(a, 0.0f);
    }
    __syncthreads();
    if (t < 10) {
        float a = bf3[t];
        for (int k = 0; k < 64; k++) a = fmaf(h2[k], Wf3[k * 10 + t], a);
        out[(size_t)gidx * 10 + t] = a;
    }
}

extern "C" void kernel_launch(void* const* d_in, const int* in_sizes, int n_in,
                              void* d_out, int out_size, void* d_ws, size_t ws_size,
                              hipStream_t stream) {
    const float* x   = (const float*)d_in[0];
    const int*  ei   = (const int*)d_in[1];
    const int*  batch= (const int*)d_in[2];
    const float* W1a = (const float*)d_in[3];  const float* b1a = (const float*)d_in[4];
    const float* W1b = (const float*)d_in[5];  const float* b1b = (const float*)d_in[6];
    const float* g1  = (const float*)d_in[7];  const float* be1 = (const float*)d_in[8];
    const float* W2a = (const float*)d_in[9];  const float* b2a = (const float*)d_in[10];
    const float* W2b = (const float*)d_in[11]; const float* b2b = (const float*)d_in[12];
    const float* g2  = (const float*)d_in[13]; const float* be2 = (const float*)d_in[14];
    const float* W3a = (const float*)d_in[15]; const float* b3a = (const float*)d_in[16];
    const float* W3b = (const float*)d_in[17]; const float* b3b = (const float*)d_in[18];
    const float* g3  = (const float*)d_in[19]; const float* be3 = (const float*)d_in[20];
    const float* Wf1 = (const float*)d_in[21]; const float* bf1 = (const float*)d_in[22];
    const float* Wf2 = (const float*)d_in[23]; const float* bf2 = (const float*)d_in[24];
    const float* Wf3 = (const float*)d_in[25]; const float* bf3 = (const float*)d_in[26];

    const int N = in_sizes[2];
    const int E = in_sizes[1] / 2;
    const int G = out_size / 10;
    const int* src = ei;
    const int* dst = ei + E;

    const int NBK = (N + BMASK) >> BSHIFT;           // buckets (391 for N=100K)
    const int CHUNK = (((E + NBLK - 1) / NBLK) + 3) & ~3;  // 4-aligned for int4

    // ---- dedicated ws regions ----
    float* B0   = (float*)d_ws;              // N*128 f32 worth (= N*256 f16)
    float* B1   = B0 + (size_t)N * 128;
    float* pool = B1 + (size_t)N * 128;      // G*32
    float* st1  = pool + (size_t)G * 32;     // 256 each
    float* st2  = st1 + 256;
    float* st3  = st2 + 256;
    int* off    = (int*)(st3 + 256);         // N+1
    int* elist  = off + (N + 1);             // E
    float* v2   = (float*)(elist + E);       // 64
    float* v3   = v2 + 64;                   // 32
    int* boff   = (int*)(v3 + 32);           // NBK+1
    int* btot   = boff + (NBK + 1);          // NBK
    f16* Wh1a   = (f16*)(btot + NBK);        // 8K
    f16* Wh1b   = Wh1a + 64 * 128;           // 16K
    f16* Wh2a   = Wh1b + 128 * 128;          // 8K
    f16* Wh2b   = Wh2a + 128 * 64;           // 4K
    f16* Wh3a   = Wh2b + 64 * 64;            // 2K
    f16* Wh3b   = Wh3a + 64 * 32;            // 1K

    // ---- CSR-phase aliases in B1 (dead before B1's activation use) ----
    int* bucketed = (int*)B1;                // E ints (12.8 MB)
    int* hist     = bucketed + E;            // NBK*NBLK ints (800 KB)

    // ---- activation aliases (stream-order safe) ----
    f16* xh    = (f16*)B0;                    // N*64  [B0 slot A]
    f16* A1    = (f16*)B1;                    // N*64  [B1 slot A] (bucketed dead)
    f16* H1    = (f16*)B0 + (size_t)N * 64;   // N*128 [B0 slot B]
    f16* Y1    = (f16*)B1 + (size_t)N * 64;   // N*128 [B1 slot B] (hist dead)
    f16* Z1    = (f16*)B0;                    // N*64  [B0 slot A] (xh dead)
    f16* H2    = (f16*)B1;                    // N*64  [B1 slot A] (A1 dead)
    f16* Y2    = (f16*)B0 + (size_t)N * 64;   // N*64  [B0 slot B] (H1 dead)
    f16* Z2    = (f16*)B0;                    // N*32  [B0 slot A] (Z1 dead)
    f16* H3    = (f16*)B1;                    // N*32  [B1 slot A] (H2 dead)
    float* Y3  = B1 + (size_t)N * 64;         // N*32 f32 [B1 slot B] (Y1 dead)

    hipMemsetAsync(pool, 0, ((size_t)G * 32 + 768) * sizeof(float), stream);

    const float invN = 1.0f / (float)N;
    const int GG = 640;

    // ---- fused setup: x->f16 + static W frags ----
    {
        int BC = (N * 16 + 255) / 256;
        setup_kernel<<<BC + 32 + 64 + 16 + 4, 256, 0, stream>>>(
            (const float4*)x, (f16x4*)xh, N * 16,
            W1a, Wh1a, W1b, Wh1b, W2b, Wh2b, W3b, Wh3b);
    }

    // ---- CSR build (bucketed, LDS atomics only) ----
    bkt_count  <<<NBLK, 256, 0, stream>>>(dst, hist, NBK, CHUNK, E);
    bkt_bscan  <<<NBK, 512, 0, stream>>>(hist, btot);
    bkt_boff   <<<1, 512, 0, stream>>>(btot, boff, off, NBK, N, E);
    bkt_scatter<<<NBLK, 256, 0, stream>>>(src, dst, hist, boff, bucketed, NBK, CHUNK, E);
    bkt_csr    <<<NBK, 512, 0, stream>>>(bucketed, boff, off, elist, N);

    // ---- Layer 1: gather(x,64) -> gemm 64->128 relu -> gemm 128->128 relu+stats
    gather_v<64, false><<<(N + 31) / 32, 256, 0, stream>>>(off, elist, xh, A1, nullptr, nullptr, N);
    gemm_mfma<64, 128, 64, false, true, true, f16><<<GG, 256, 0, stream>>>(A1, Wh1a, b1a, H1, nullptr, N);
    gemm_mfma<128, 128, 64, true, true, true, f16><<<GG, 256, 0, stream>>>(H1, Wh1b, b1b, Y1, st1, N);

    // ---- Layer 2 (commuted): Z1 = Y1 @ diag(sc1) W2a; gather+affine+relu -> H2
    layerprep_kernel<<<33, 256, 0, stream>>>(W2a, Wh2a, 128, 64, st1, g1, be1, v2, invN);
    gemm_mfma<128, 64, 64, false, false, false, f16><<<GG, 256, 0, stream>>>(Y1, Wh2a, nullptr, Z1, nullptr, N);
    gather_v<64, true><<<(N + 31) / 32, 256, 0, stream>>>(off, elist, Z1, H2, v2, b2a, N);
    gemm_mfma<64, 64, 64, true, true, true, f16><<<GG, 256, 0, stream>>>(H2, Wh2b, b2b, Y2, st2, N);

    // ---- Layer 3 (commuted): Z2 = Y2 @ diag(sc2) W3a; gather+affine+relu -> H3
    layerprep_kernel<<<9, 256, 0, stream>>>(W3a, Wh3a, 64, 32, st2, g2, be2, v3, invN);
    gemm_mfma<64, 32, 32, false, false, false, f16><<<GG, 256, 0, stream>>>(Y2, Wh3a, nullptr, Z2, nullptr, N);
    gather_v<32, true><<<(N + 63) / 64, 256, 0, stream>>>(off, elist, Z2, H3, v3, b3a, N);
    gemm_mfma<32, 32, 32, true, true, true, float><<<GG, 256, 0, stream>>>(H3, Wh3b, b3b, Y3, st3, N);

    // ---- BN3 + segmented pool ----
    bn_pool_kernel<<<(N + 511) / 512, 256, 0, stream>>>(Y3, st3, g3, be3, batch, pool, N, invN);

    // ---- pooled MLP head ----
    fc_kernel<<<G, 128, 0, stream>>>(pool, Wf1, bf1, Wf2, bf2, Wf3, bf3, (float*)d_out);
}